// Round 1
// baseline (327.276 us; speedup 1.0000x reference)
//
#include <hip/hip_runtime.h>
#include <math.h>

// DeformConv2D: b=4, c=64, H=W=128, KS=3, PAD=1, N=9, 18 offset channels, 64 out ch.
// out[b,o,h,w] = sum_{c,n} W_conv[o,c,n] * bilinear_sample(xpad, p(b,n,h,w), c)
// p_row = h+1 + (n/3 - 1) + off_row(n),  p_col = w+1 + (n%3 - 1) + off_col(n)
// off_row(n) = offset conv channel 2n, off_col(n) = channel 2n+1 (the idx reorder).

#define B_   4
#define C_   64
#define H_   128
#define W_   128
#define HP_  130            // padded spatial
#define NPIX (B_*H_*W_)     // 65536

// workspace layout (float element offsets)
#define XP_OFF   0
#define XP_CNT   (B_*HP_*HP_*C_)        // 4,326,400  padded NHWC x
#define OFFS_OFF (XP_OFF + XP_CNT)
#define OFFS_CNT (NPIX*18)              // 1,179,648  per-pixel offsets [pix][18]
#define WT4_OFF  (OFFS_OFF + OFFS_CNT)
#define WT4_CNT  (576*64)               // 36,864     Wt4[g][o][j] = W_conv[o][cn=g*4+j]
#define WOT_OFF  (WT4_OFF + WT4_CNT)
#define WOT_CNT  (9*64*18)              // 10,368     Wot[tap][c][k] reordered offset weights
// total = 5,553,280 floats = 22,213,120 bytes of d_ws

// ---------------------------------------------------------------- K0: weight prep
__global__ __launch_bounds__(256) void prep_weights(const float* __restrict__ W_off,
                                                    const float* __restrict__ W_conv,
                                                    float* __restrict__ ws) {
    int idx = blockIdx.x * 256 + threadIdx.x;
    if (idx < WT4_CNT) {
        // Wt4[(g*64+o)*4+j] = W_conv[o][c][n],  cn = g*4+j, n = cn/64, c = cn%64  (cn = n*64+c)
        int j = idx & 3;
        int o = (idx >> 2) & 63;
        int g = idx >> 8;
        int cn = g * 4 + j;
        int n = cn >> 6, c = cn & 63;
        ws[WT4_OFF + idx] = W_conv[(o * 64 + c) * 9 + n];
    }
    int idx2 = idx - WT4_CNT;
    if (idx2 >= 0 && idx2 < WOT_CNT) {
        // Wot[tap][c][k]; output k<9 -> orig offset channel 2k (row), k>=9 -> 2(k-9)+1 (col)
        int k = idx2 % 18;
        int c = (idx2 / 18) & 63;
        int tap = idx2 / (18 * 64);
        int ko = (k < 9) ? 2 * k : 2 * (k - 9) + 1;
        ws[WOT_OFF + idx2] = W_off[(ko * 64 + c) * 9 + tap];
    }
}

// ---------------------------------------------------------------- K1: pad + NCHW->NHWC
__global__ __launch_bounds__(256) void pad_transpose(const float* __restrict__ x,
                                                     float* __restrict__ ws) {
    int idx = blockIdx.x * 256 + threadIdx.x;   // grid sized exactly XP_CNT/256
    int c  = idx & 63;
    int t  = idx >> 6;
    int wp = t % HP_;
    int t2 = t / HP_;
    int hp = t2 % HP_;
    int b  = t2 / HP_;
    float v = 0.f;
    if (hp >= 1 && hp <= H_ && wp >= 1 && wp <= W_)
        v = x[((b * 64 + c) * 128 + (hp - 1)) * 128 + (wp - 1)];
    ws[XP_OFF + idx] = v;   // xp_t[b][hp][wp][c], zero border
}

// ---------------------------------------------------------------- K2: offset conv (fp32)
// block = 256 = 4 waves; each wave = 64 pixels (consecutive w), wave q handles c in [q*16, q*16+16)
// weights are wave-uniform -> scalar loads; 18 fp32 accumulators per thread; LDS combine of 4 quarters.
__global__ __launch_bounds__(256) void offsets_kernel(const float* __restrict__ b_off,
                                                      float* __restrict__ ws) {
    const float* xp  = ws + XP_OFF;
    const float* Wot = ws + WOT_OFF;
    float* offs      = ws + OFFS_OFF;
    __shared__ float part[256][19];   // +1 pad: stride 19 is conflict-free

    int lane = threadIdx.x & 63;
    int q    = threadIdx.x >> 6;      // wave id == c-quarter (wave-uniform)
    int pix  = blockIdx.x * 64 + lane;
    int w = pix & 127, h = (pix >> 7) & 127, b = pix >> 14;

    float acc[18];
#pragma unroll
    for (int k = 0; k < 18; k++) acc[k] = 0.f;

    for (int tap = 0; tap < 9; tap++) {
        int ty = tap / 3, tx = tap % 3;
        const float* xrow = xp + (((b * HP_) + (h + ty)) * HP_ + (w + tx)) * 64 + q * 16;
        const float* wrow = Wot + (tap * 64 + q * 16) * 18;
#pragma unroll
        for (int c4 = 0; c4 < 4; c4++) {
            float4 xv = *(const float4*)(xrow + c4 * 4);
#pragma unroll
            for (int k = 0; k < 18; k++) {
                acc[k] = fmaf(wrow[(c4 * 4 + 0) * 18 + k], xv.x,
                         fmaf(wrow[(c4 * 4 + 1) * 18 + k], xv.y,
                         fmaf(wrow[(c4 * 4 + 2) * 18 + k], xv.z,
                         fmaf(wrow[(c4 * 4 + 3) * 18 + k], xv.w, acc[k]))));
            }
        }
    }
#pragma unroll
    for (int k = 0; k < 18; k++) part[threadIdx.x][k] = acc[k];
    __syncthreads();

    int pixbase = blockIdx.x * 64;
    for (int lin = threadIdx.x; lin < 64 * 18; lin += 256) {
        int pl = lin / 18, k = lin % 18;
        float v = part[pl][k] + part[64 + pl][k] + part[128 + pl][k] + part[192 + pl][k];
        int ko = (k < 9) ? 2 * k : 2 * (k - 9) + 1;
        v += b_off[ko];
        offs[(pixbase + pl) * 18 + k] = v;   // coalesced: lin-consecutive -> addr-consecutive
    }
}

// ---------------------------------------------------------------- K3: sample + contraction
// block = 256 = 4 waves, 16 pixels/block (same image row), wave handles 4 pixels.
// phase 1: lane = c, coalesced 256B corner-row reads, bilinear -> LDS xoff[wv][p][n*64+c]
// phase 2: lane = o, acc[4]; Wt4 float4 coalesced (L2-resident), xoff float4 LDS broadcast.
__global__ __launch_bounds__(256) void main_kernel(float* __restrict__ out,
                                                   const float* __restrict__ ws) {
    const float* xp   = ws + XP_OFF;
    const float* offs = ws + OFFS_OFF;
    const float* Wt4  = ws + WT4_OFF;
    __shared__ float xoff[4][4][576];   // 36,864 B -> 4 blocks/CU

    int lane = threadIdx.x & 63;
    int wv   = threadIdx.x >> 6;
    int pixbase = blockIdx.x * 16 + wv * 4;

    // ---- phase 1: gather/bilinear (fp32; must exactly mirror reference decisions)
    for (int p = 0; p < 4; p++) {
        int pix = pixbase + p;
        int w = pix & 127, h = (pix >> 7) & 127, b = pix >> 14;
        const float* po = offs + pix * 18;
        const float* b0 = xp + b * (HP_ * HP_ * 64);
#pragma unroll
        for (int n = 0; n < 9; n++) {
            float orow = po[n], ocol = po[9 + n];
            // p = (h+1) + (n/3 - 1) + off  ==  h + n/3 + off
            float pr = (float)(h + (n / 3)) + orow;
            float pc = (float)(w + (n % 3)) + ocol;
            float flr = floorf(pr), flc = floorf(pc);
            float qlt_r = fminf(fmaxf(flr, 0.f), 129.f);
            float qlt_c = fminf(fmaxf(flc, 0.f), 129.f);
            float qrb_r = fminf(fmaxf(flr + 1.f, 0.f), 129.f);
            float qrb_c = fminf(fmaxf(flc + 1.f, 0.f), 129.f);
            bool mr = (pr < 1.f) || (pr > 128.f);   // mask vs ORIGINAL p
            bool mc = (pc < 1.f) || (pc > 128.f);
            float pr2 = mr ? flr : pr; pr2 = fminf(fmaxf(pr2, 0.f), 129.f);
            float pc2 = mc ? flc : pc; pc2 = fminf(fmaxf(pc2, 0.f), 129.f);
            float wr_lt = 1.f + (qlt_r - pr2);
            float wr_rb = 1.f - (qrb_r - pr2);
            float wc_lt = 1.f + (qlt_c - pc2);
            float wc_rb = 1.f - (qrb_c - pc2);
            int ilt_r = (int)qlt_r, ilt_c = (int)qlt_c;
            int irb_r = (int)qrb_r, irb_c = (int)qrb_c;
            float x_lt = b0[(ilt_r * HP_ + ilt_c) * 64 + lane];
            float x_rb = b0[(irb_r * HP_ + irb_c) * 64 + lane];
            float x_lb = b0[(ilt_r * HP_ + irb_c) * 64 + lane];  // (lt row, rb col)
            float x_rt = b0[(irb_r * HP_ + ilt_c) * 64 + lane];  // (rb row, lt col)
            float val = fmaf(wr_lt * wc_lt, x_lt,
                        fmaf(wr_rb * wc_rb, x_rb,
                        fmaf(wr_lt * wc_rb, x_lb,
                             wr_rb * wc_lt * x_rt)));
            xoff[wv][p][n * 64 + lane] = val;
        }
    }
    // same-wave LDS produce->consume: compiler-inserted lgkmcnt waits suffice (no barrier needed)

    // ---- phase 2: out[o] = sum_cn Wt[cn][o] * xoff[p][cn]
    float acc0 = 0.f, acc1 = 0.f, acc2 = 0.f, acc3 = 0.f;
    for (int g = 0; g < 144; g++) {
        float4 wq = *(const float4*)(Wt4 + (g * 64 + lane) * 4);
        float4 x0 = *(const float4*)(&xoff[wv][0][g * 4]);
        float4 x1 = *(const float4*)(&xoff[wv][1][g * 4]);
        float4 x2 = *(const float4*)(&xoff[wv][2][g * 4]);
        float4 x3 = *(const float4*)(&xoff[wv][3][g * 4]);
        acc0 = fmaf(wq.x, x0.x, fmaf(wq.y, x0.y, fmaf(wq.z, x0.z, fmaf(wq.w, x0.w, acc0))));
        acc1 = fmaf(wq.x, x1.x, fmaf(wq.y, x1.y, fmaf(wq.z, x1.z, fmaf(wq.w, x1.w, acc1))));
        acc2 = fmaf(wq.x, x2.x, fmaf(wq.y, x2.y, fmaf(wq.z, x2.z, fmaf(wq.w, x2.w, acc2))));
        acc3 = fmaf(wq.x, x3.x, fmaf(wq.y, x3.y, fmaf(wq.z, x3.z, fmaf(wq.w, x3.w, acc3))));
    }

#pragma unroll
    for (int p = 0; p < 4; p++) {
        int pix = pixbase + p;
        int w = pix & 127, h = (pix >> 7) & 127, b = pix >> 14;
        float v = (p == 0) ? acc0 : (p == 1) ? acc1 : (p == 2) ? acc2 : acc3;
        out[(((size_t)b * 64 + lane) * 128 + h) * 128 + w] = v;
    }
}

// ---------------------------------------------------------------- launch
extern "C" void kernel_launch(void* const* d_in, const int* in_sizes, int n_in,
                              void* d_out, int out_size, void* d_ws, size_t ws_size,
                              hipStream_t stream) {
    const float* x      = (const float*)d_in[0];
    const float* W_off  = (const float*)d_in[1];
    const float* b_off  = (const float*)d_in[2];
    const float* W_conv = (const float*)d_in[3];
    float* ws  = (float*)d_ws;     // needs 22,213,120 bytes
    float* out = (float*)d_out;

    hipLaunchKernelGGL(prep_weights, dim3((WT4_CNT + WOT_CNT + 255) / 256), dim3(256), 0, stream,
                       W_off, W_conv, ws);
    hipLaunchKernelGGL(pad_transpose, dim3(XP_CNT / 256), dim3(256), 0, stream, x, ws);
    hipLaunchKernelGGL(offsets_kernel, dim3(NPIX / 64), dim3(256), 0, stream, b_off, ws);
    hipLaunchKernelGGL(main_kernel, dim3(NPIX / 16), dim3(256), 0, stream, out, ws);
}

// Round 2
// 159.850 us; speedup vs baseline: 2.0474x; 2.0474x over previous
//
#include <hip/hip_runtime.h>
#include <math.h>

// DeformConv2D MI355X: b=4,c=64,H=W=128,KS=3,N=9 -> out[b,o,h,w] = sum_{c,n} W[o,c,n]*bilin(xpad,p)
// R2: bf16 MFMA contraction (32x32x16), split scalar-bilinear/gather phases, bf16 gather copy,
//     LDS weights for offset conv, LDS-tiled pad/transpose. Offsets stay fp32 (decision-exact).

typedef __attribute__((ext_vector_type(8)))  short short8;
typedef __attribute__((ext_vector_type(4)))  short short4_t;
typedef __attribute__((ext_vector_type(16))) float float16;

#define HP_ 130
#define NPIX 65536
#define XS_STRIDE 580   // 576 + 4 pad bf16: dword stride 290 ≡ 2 mod 32 -> b64 reads 2-way (free)

// workspace layout (byte offsets)
#define XP_B    0u           // fp32 padded NHWC x : 4*130*130*64 floats = 17,305,600 B
#define XPB_B   17305600u    // bf16 copy          : 8,652,800 B
#define OFFS_B  25958400u    // offs[pix][18] fp32 : 4,718,592 B
#define WOT_B   30676992u    // Wot20[576][20] fp32: 46,080 B
#define WBB_B   30723072u    // Wb bf16 MFMA B-frags: 73,728 B   (end 30,796,800)

__device__ inline unsigned short f2bf(float f) {
    unsigned int u = __float_as_uint(f);
    u += 0x7fffu + ((u >> 16) & 1u);           // RNE
    return (unsigned short)(u >> 16);
}
__device__ inline float bfhi2f(unsigned int v) { return __uint_as_float(v & 0xffff0000u); }
__device__ inline float bflo2f(unsigned int v) { return __uint_as_float(v << 16); }

// ---------------------------------------------------------------- K0: weight prep
__global__ __launch_bounds__(256) void prep_weights(const float* __restrict__ W_off,
                                                    const float* __restrict__ W_conv,
                                                    char* __restrict__ wsb) {
    float* Wot = (float*)(wsb + WOT_B);
    unsigned short* Wb = (unsigned short*)(wsb + WBB_B);
    int idx = blockIdx.x * 256 + threadIdx.x;
    if (idx < 576 * 20) {
        // Wot20[(q*9+tap)*16+cq][20]; k<9 -> offset ch 2k (row), k in 9..17 -> 2(k-9)+1 (col)
        int k = idx % 20, R = idx / 20;
        int q = R / 144, rem = R % 144, tap = rem / 16, cq = rem % 16;
        int c = q * 16 + cq;
        float v = 0.f;
        if (k < 18) { int ko = (k < 9) ? 2 * k : 2 * (k - 9) + 1; v = W_off[(ko * 64 + c) * 9 + tap]; }
        Wot[idx] = v;
    }
    int e = idx - 576 * 20;
    if (e >= 0 && e < 36864) {
        // Wb[((nt*36+ks)*64+lane)*8+j] = bf16( B[k][n] ),  k=ks*16+(lane>>5)*8+j, n=nt*32+(lane&31)
        int j = e & 7, lane = (e >> 3) & 63, t2 = e >> 9;
        int ks = t2 % 36, nt = t2 / 36;
        int k = ks * 16 + ((lane >> 5) << 3) + j;       // k = tap*64 + c (im2col order)
        int n = nt * 32 + (lane & 31);                  // n = out channel
        Wb[e] = f2bf(W_conv[(n * 64 + (k & 63)) * 9 + (k >> 6)]);
    }
}

// ---------------------------------------------------------------- K1: pad + NCHW->NHWC (fp32 + bf16)
__global__ __launch_bounds__(256) void pad_transpose(const float* __restrict__ x,
                                                     char* __restrict__ wsb) {
    float* xp = (float*)(wsb + XP_B);
    unsigned short* xpb = (unsigned short*)(wsb + XPB_B);
    __shared__ float tile[64][129];     // +1 pad: transposed reads conflict-free
    int t = threadIdx.x;
    int hp = blockIdx.x % 130, b = blockIdx.x / 130;
    int rowbase = ((b * 130 + hp) * 130) * 64;
    if (hp == 0 || hp == 129) {
        for (int i = t; i < 130 * 64; i += 256) { xp[rowbase + i] = 0.f; xpb[rowbase + i] = 0; }
        return;
    }
    int h = hp - 1;
    {
        int w = t & 127, chalf = t >> 7;
        for (int cc = 0; cc < 64; cc += 2) {
            int c = cc + chalf;
            tile[c][w] = x[(((b * 64 + c) * 128) + h) * 128 + w];   // coalesced over w
        }
    }
    __syncthreads();
    {
        int c = t & 63, wq = t >> 6;
        if (wq == 0) { xp[rowbase + c] = 0.f; xpb[rowbase + c] = 0; }                       // wp=0
        if (wq == 1) { xp[rowbase + 129 * 64 + c] = 0.f; xpb[rowbase + 129 * 64 + c] = 0; } // wp=129
        for (int w = wq; w < 128; w += 4) {
            float v = tile[c][w];
            int a = rowbase + (w + 1) * 64 + c;     // coalesced over c
            xp[a] = v; xpb[a] = f2bf(v);
        }
    }
}

// ---------------------------------------------------------------- K2: offset conv (fp32, exact)
// 4 waves, 64 pixels/block; wave q = channel quarter; weights in LDS (b128 broadcast), k padded to 20
__global__ __launch_bounds__(256) void offsets_kernel(const float* __restrict__ b_off,
                                                      char* __restrict__ wsb) {
    const float* xp   = (const float*)(wsb + XP_B);
    const float* WotG = (const float*)(wsb + WOT_B);
    float* offs       = (float*)(wsb + OFFS_B);
    __shared__ float Wl[576 * 20];      // 46,080 B
    __shared__ float part[256][22];     // stride 22: b64 writes 2-way only
    int t = threadIdx.x;
    for (int i = t; i < 576 * 20; i += 256) Wl[i] = WotG[i];
    __syncthreads();
    int lane = t & 63, q = t >> 6;
    int pix = blockIdx.x * 64 + lane;
    int w = pix & 127, h = (pix >> 7) & 127, b = pix >> 14;
    float acc[20];
#pragma unroll
    for (int k = 0; k < 20; k++) acc[k] = 0.f;
#pragma unroll
    for (int tap = 0; tap < 9; tap++) {
        int ty = tap / 3, tx = tap % 3;
        const float* xrow = xp + (((b * 130) + (h + ty)) * 130 + (w + tx)) * 64 + q * 16;
        const float* wbase = Wl + ((q * 9 + tap) * 16) * 20;
#pragma unroll
        for (int c4 = 0; c4 < 4; c4++) {
            float4 xv = *(const float4*)(xrow + c4 * 4);
#pragma unroll
            for (int cn = 0; cn < 4; cn++) {
                const float* wr = wbase + (c4 * 4 + cn) * 20;
                float xv1 = (cn == 0) ? xv.x : (cn == 1) ? xv.y : (cn == 2) ? xv.z : xv.w;
#pragma unroll
                for (int kq = 0; kq < 5; kq++) {
                    float4 wv4 = *(const float4*)(wr + kq * 4);      // uniform -> LDS broadcast
                    acc[kq * 4 + 0] = fmaf(wv4.x, xv1, acc[kq * 4 + 0]);
                    acc[kq * 4 + 1] = fmaf(wv4.y, xv1, acc[kq * 4 + 1]);
                    acc[kq * 4 + 2] = fmaf(wv4.z, xv1, acc[kq * 4 + 2]);
                    acc[kq * 4 + 3] = fmaf(wv4.w, xv1, acc[kq * 4 + 3]);
                }
            }
        }
    }
#pragma unroll
    for (int k = 0; k < 20; k++) part[t][k] = acc[k];
    __syncthreads();
    int pixbase = blockIdx.x * 64;
    for (int lin = t; lin < 64 * 18; lin += 256) {
        int pl = (lin * 3641) >> 16;            // /18
        int k = lin - pl * 18;
        float v = part[pl][k] + part[64 + pl][k] + part[128 + pl][k] + part[192 + pl][k];
        int ko = (k < 9) ? 2 * k : 2 * (k - 9) + 1;
        offs[(pixbase + pl) * 18 + k] = v + b_off[ko];
    }
}

// ---------------------------------------------------------------- K3: sample + MFMA contraction
// block=256 (4 waves), 32 pixels (same row). A: per-(pixel,tap) corners+weights -> LDS.
// B: gather bf16 x, bilinear fp32, bf16 samples -> xs LDS. C: 32x32x16 bf16 MFMA, K=576 split 2.
__global__ __launch_bounds__(256) void main_kernel(float* __restrict__ out,
                                                   const char* __restrict__ wsb) {
    const unsigned short* xpb = (const unsigned short*)(wsb + XPB_B);
    const float* offs = (const float*)(wsb + OFFS_B);
    const short8* Wb  = (const short8*)(wsb + WBB_B);
    __shared__ __attribute__((aligned(16))) char smem[46336];
    unsigned short* xs = (unsigned short*)smem;              // [32][XS_STRIDE] bf16 = 37,120 B
    int4*   cdatL = (int4*)(smem + 37120);                   // [288] corner linear offsets
    float4* cdatG = (float4*)(smem + 41728);                 // [288] bilinear weights
    float*  obuf  = (float*)(smem + 37120);                  // [2][32][33] aliased (cdat dead)

    int t = threadIdx.x;
    int pixbase = blockIdx.x * 32;
    int w0 = pixbase & 127, h0 = (pixbase >> 7) & 127, bimg = pixbase >> 14;

    // ---- phase A: per-(pixel,tap) scalar bilinear setup (exact fp32, mirrors reference)
    for (int it = t; it < 288; it += 256) {
        int p = (it * 7282) >> 16;              // /9
        int n = it - p * 9;
        int pix = pixbase + p;
        float orow = offs[pix * 18 + n], ocol = offs[pix * 18 + 9 + n];
        float pr = (float)(h0 + (n / 3)) + orow;
        float pc = (float)(w0 + p + (n % 3)) + ocol;
        float flr = floorf(pr), flc = floorf(pc);
        float qlt_r = fminf(fmaxf(flr, 0.f), 129.f);
        float qlt_c = fminf(fmaxf(flc, 0.f), 129.f);
        float qrb_r = fminf(fmaxf(flr + 1.f, 0.f), 129.f);
        float qrb_c = fminf(fmaxf(flc + 1.f, 0.f), 129.f);
        bool mr = (pr < 1.f) || (pr > 128.f);
        bool mc = (pc < 1.f) || (pc > 128.f);
        float pr2 = mr ? flr : pr; pr2 = fminf(fmaxf(pr2, 0.f), 129.f);
        float pc2 = mc ? flc : pc; pc2 = fminf(fmaxf(pc2, 0.f), 129.f);
        float wr_lt = 1.f + (qlt_r - pr2);
        float wr_rb = 1.f - (qrb_r - pr2);
        float wc_lt = 1.f + (qlt_c - pc2);
        float wc_rb = 1.f - (qrb_c - pc2);
        int ilt_r = (int)qlt_r, ilt_c = (int)qlt_c;
        int irb_r = (int)qrb_r, irb_c = (int)qrb_c;
        cdatL[it] = make_int4((ilt_r * 130 + ilt_c) * 64, (irb_r * 130 + irb_c) * 64,
                              (ilt_r * 130 + irb_c) * 64, (irb_r * 130 + ilt_c) * 64);
        cdatG[it] = make_float4(wr_lt * wc_lt, wr_rb * wc_rb, wr_lt * wc_rb, wr_rb * wc_lt);
    }
    __syncthreads();

    // ---- phase B: gather (2 items/wave-load: 32 lanes x 2ch each = 256B lines)
    int lane = t & 63, wv = t >> 6;
    int half = lane >> 5, cp = lane & 31;
    const unsigned short* bplane = xpb + bimg * (130 * 130 * 64);
    int base = wv * 72;
#pragma unroll 4
    for (int i = 0; i < 36; i++) {
        int item = base + 2 * i + half;
        int4 L = cdatL[item];
        float4 G = cdatG[item];
        unsigned int vlt = *(const unsigned int*)(bplane + L.x + 2 * cp);
        unsigned int vrb = *(const unsigned int*)(bplane + L.y + 2 * cp);
        unsigned int vlb = *(const unsigned int*)(bplane + L.z + 2 * cp);
        unsigned int vrt = *(const unsigned int*)(bplane + L.w + 2 * cp);
        float lo = fmaf(G.x, bflo2f(vlt), fmaf(G.y, bflo2f(vrb), fmaf(G.z, bflo2f(vlb), G.w * bflo2f(vrt))));
        float hi = fmaf(G.x, bfhi2f(vlt), fmaf(G.y, bfhi2f(vrb), fmaf(G.z, bfhi2f(vlb), G.w * bfhi2f(vrt))));
        int p = (item * 7282) >> 16;
        int n = item - p * 9;
        unsigned int pk = (unsigned int)f2bf(lo) | ((unsigned int)f2bf(hi) << 16);
        *(unsigned int*)(xs + p * XS_STRIDE + n * 64 + 2 * cp) = pk;
    }
    __syncthreads();

    // ---- phase C: MFMA. wave wv: nt = N-tile (32 outs), kh = K-half (288)
    int nt = wv & 1, kh = wv >> 1;
    float16 acc;
#pragma unroll
    for (int r = 0; r < 16; r++) acc[r] = 0.f;
    int m = lane & 31;
    for (int i2 = 0; i2 < 18; i2++) {
        int ksg = kh * 18 + i2;
        int baseE = m * XS_STRIDE + ksg * 16 + ((lane >> 5) << 3);
        short4_t a0 = *(const short4_t*)(xs + baseE);        // b64: stride 290dw -> 2-way only
        short4_t a1 = *(const short4_t*)(xs + baseE + 4);
        short8 af;
        af[0] = a0[0]; af[1] = a0[1]; af[2] = a0[2]; af[3] = a0[3];
        af[4] = a1[0]; af[5] = a1[1]; af[6] = a1[2]; af[7] = a1[3];
        short8 bfv = Wb[(nt * 36 + ksg) * 64 + lane];        // coalesced 1KB, L2-resident
        acc = __builtin_amdgcn_mfma_f32_32x32x16_bf16(af, bfv, acc, 0, 0, 0);
    }
    // K-half combine via obuf (aliases cdat: all cdat reads completed before phase-B barrier)
    if (kh == 1) {
#pragma unroll
        for (int r = 0; r < 16; r++) {
            int mrow = (r & 3) + 8 * (r >> 2) + 4 * (lane >> 5);
            obuf[nt * 1056 + mrow * 33 + (lane & 31)] = acc[r];
        }
    }
    __syncthreads();
    if (kh == 0) {
#pragma unroll
        for (int r = 0; r < 16; r++) {
            int mrow = (r & 3) + 8 * (r >> 2) + 4 * (lane >> 5);
            int oi = nt * 1056 + mrow * 33 + (lane & 31);
            obuf[oi] = acc[r] + obuf[oi];
        }
    }
    __syncthreads();
    // coalesced store: 32 consecutive w per o
#pragma unroll
    for (int i = 0; i < 8; i++) {
        int lin = i * 256 + t;
        int o = lin >> 5, p = lin & 31;
        float v = obuf[(o >> 5) * 1056 + p * 33 + (o & 31)];
        out[((bimg * 64 + o) << 14) + (h0 << 7) + w0 + p] = v;
    }
}

// ---------------------------------------------------------------- launch
extern "C" void kernel_launch(void* const* d_in, const int* in_sizes, int n_in,
                              void* d_out, int out_size, void* d_ws, size_t ws_size,
                              hipStream_t stream) {
    const float* x      = (const float*)d_in[0];
    const float* W_off  = (const float*)d_in[1];
    const float* b_off  = (const float*)d_in[2];
    const float* W_conv = (const float*)d_in[3];
    char* wsb  = (char*)d_ws;            // needs 30,796,800 B
    float* out = (float*)d_out;

    hipLaunchKernelGGL(prep_weights, dim3(190), dim3(256), 0, stream, W_off, W_conv, wsb);
    hipLaunchKernelGGL(pad_transpose, dim3(4 * 130), dim3(256), 0, stream, x, wsb);
    hipLaunchKernelGGL(offsets_kernel, dim3(NPIX / 64), dim3(256), 0, stream, b_off, wsb);
    hipLaunchKernelGGL(main_kernel, dim3(NPIX / 32), dim3(256), 0, stream, out, wsb);
}

// Round 3
// 140.647 us; speedup vs baseline: 2.3269x; 1.1365x over previous
//
#include <hip/hip_runtime.h>
#include <hip/hip_bf16.h>
#include <math.h>

// DeformConv2D MI355X: b=4,c=64,H=W=128,KS=3,N=9 -> out[b,o,h,w] = sum_{c,n} W[o,c,n]*bilin(xpad,p)
// R3: offset conv via split-bf16 MFMA (Ah*Bh + Ah*Bl + Al*Bh ~ fp32 accuracy), prep folded into
//     pad kernel, main kernel phase-B VALU diet (byte offsets, packed bf16 cvt). 3 launches.

typedef __attribute__((ext_vector_type(8)))  short short8;
typedef __attribute__((ext_vector_type(4)))  short short4_t;
typedef __attribute__((ext_vector_type(16))) float float16;

#define NPIX 65536
#define XS_STRIDE 580   // xs leading dim (bf16): dword stride 290 = 2 mod 32 -> 2-way (free)

// workspace layout (byte offsets)
#define XPB_B   0u           // bf16 hi padded NHWC x : 4*130*130*64*2 = 8,652,800 B
#define XPL_B   8652800u     // bf16 lo residual      : 8,652,800 B
#define OFFS_B  17305600u    // offs[pix][18] fp32    : 4,718,592 B
#define WBB_B   22024192u    // W_conv bf16 MFMA B-frags: 73,728 B
#define WOH_B   22097920u    // W_off hi B-frags      : 36,864 B
#define WOL_B   22134784u    // W_off lo B-frags      : 36,864 B   (end 22,171,648)

__device__ inline unsigned short f2bf(float f) {
    unsigned int u = __float_as_uint(f);
    u += 0x7fffu + ((u >> 16) & 1u);           // RNE
    return (unsigned short)(u >> 16);
}
__device__ inline float bfhi2f(unsigned int v) { return __uint_as_float(v & 0xffff0000u); }
__device__ inline float bflo2f(unsigned int v) { return __uint_as_float(v << 16); }

// ---------------------------------------------------------------- K1: pad/transpose + weight prep
// blocks 0..519: pad + NCHW->NHWC, split x into hi/lo bf16. blocks 520..535: weight fragments.
__global__ __launch_bounds__(256) void pad_prep(const float* __restrict__ x,
                                                const float* __restrict__ W_off,
                                                const float* __restrict__ W_conv,
                                                char* __restrict__ wsb) {
    unsigned short* xpb = (unsigned short*)(wsb + XPB_B);
    unsigned short* xpl = (unsigned short*)(wsb + XPL_B);
    int t = threadIdx.x;
    if (blockIdx.x >= 520) {   // ---- weight prep: 16 blocks x 3456 items
        unsigned short* Wb  = (unsigned short*)(wsb + WBB_B);
        unsigned short* Woh = (unsigned short*)(wsb + WOH_B);
        unsigned short* Wol = (unsigned short*)(wsb + WOL_B);
        int wb = blockIdx.x - 520;
        for (int ii = t; ii < 3456; ii += 256) {
            int e = wb * 3456 + ii;
            if (e < 36864) {
                // Wb[((nt*36+ks)*64+lane)*8+j] = bf16(W_conv B-frag), k=ks*16+(lane>>5)*8+j
                int j = e & 7, lane = (e >> 3) & 63, t2 = e >> 9;
                int ks = t2 % 36, nt = t2 / 36;
                int k = ks * 16 + ((lane >> 5) << 3) + j;
                int n = nt * 32 + (lane & 31);
                Wb[e] = f2bf(W_conv[(n * 64 + (k & 63)) * 9 + (k >> 6)]);
            } else {
                int e2 = e - 36864;     // W_off hi/lo frags, N=32 (18 used)
                int j = e2 & 7, lane = (e2 >> 3) & 63, ksg = e2 >> 9;
                int k = ksg * 16 + ((lane >> 5) << 3) + j;
                int c = k & 63, tap = k >> 6, n = lane & 31;
                float v = 0.f;
                if (n < 18) { int ko = (n < 9) ? 2 * n : 2 * (n - 9) + 1; v = W_off[(ko * 64 + c) * 9 + tap]; }
                unsigned short hi = f2bf(v);
                Woh[e2] = hi;
                Wol[e2] = f2bf(v - bfhi2f((unsigned int)hi << 16));
            }
        }
        return;
    }
    __shared__ float tile[64][129];
    int hp = blockIdx.x % 130, b = blockIdx.x / 130;
    int rowbase = ((b * 130 + hp) * 130) * 64;
    if (hp == 0 || hp == 129) {
        for (int i = t; i < 130 * 32; i += 256) {   // dword-wide zeroing
            ((unsigned*)(xpb + rowbase))[i] = 0u;
            ((unsigned*)(xpl + rowbase))[i] = 0u;
        }
        return;
    }
    int h = hp - 1;
    {
        int w = t & 127, chalf = t >> 7;
        for (int cc = 0; cc < 64; cc += 2) {
            int c = cc + chalf;
            tile[c][w] = x[(((b * 64 + c) * 128) + h) * 128 + w];   // coalesced over w
        }
    }
    __syncthreads();
    {
        int c = t & 63, wq = t >> 6;
        if (wq == 0) { xpb[rowbase + c] = 0; xpl[rowbase + c] = 0; }
        if (wq == 1) { xpb[rowbase + 129 * 64 + c] = 0; xpl[rowbase + 129 * 64 + c] = 0; }
        for (int w = wq; w < 128; w += 4) {
            float v = tile[c][w];
            int a = rowbase + (w + 1) * 64 + c;
            unsigned short hi = f2bf(v);
            xpb[a] = hi;
            xpl[a] = f2bf(v - bfhi2f((unsigned int)hi << 16));
        }
    }
}

// ---------------------------------------------------------------- K2: offset conv via split-bf16 MFMA
// block = 256 (4 waves), 32 pixels (one row). Stage x hi/lo rows h..h+2, cols w0..w0+33 to LDS.
// M=32 px, N=32 (18 used), K=576 split 4 ways over waves; 3 MFMA products per K-step.
#define K2_WS 68        // wp stride elems: 34 dw = 2 mod 32 -> 2-way (free)
#define K2_RS 2312      // row stride elems (34*68)
__global__ __launch_bounds__(256) void offsets_mfma(const float* __restrict__ b_off,
                                                    char* __restrict__ wsb) {
    const unsigned* xpb = (const unsigned*)(wsb + XPB_B);
    const unsigned* xpl = (const unsigned*)(wsb + XPL_B);
    const short8* Woh = (const short8*)(wsb + WOH_B);
    const short8* Wol = (const short8*)(wsb + WOL_B);
    float* offs = (float*)(wsb + OFFS_B);
    __shared__ __attribute__((aligned(16))) unsigned short sstage[2 * K2_RS * 3];  // 27,744 B
    unsigned short* xh = sstage;
    unsigned short* xl = sstage + 3 * K2_RS;

    int t = threadIdx.x;
    int pixbase = blockIdx.x * 32;
    int w0 = pixbase & 127, h0 = (pixbase >> 7) & 127, bimg = pixbase >> 14;

    // ---- stage 3 rows x 34 cols x 64 ch (dword = 2 ch); global fully coalesced
    for (int i = t; i < 3264; i += 256) {
        int row = i / 1088, rem = i - row * 1088;
        int wp = rem >> 5, cd = rem & 31;
        int g = ((bimg * 130 + h0 + row) * 130 + (w0 + wp)) * 32 + cd;
        int d = row * (K2_RS / 2) + wp * (K2_WS / 2) + cd;
        ((unsigned*)xh)[d] = xpb[g];
        ((unsigned*)xl)[d] = xpl[g];
    }
    __syncthreads();

    int lane = t & 63, wv = t >> 6;
    int m = lane & 31, half8 = (lane >> 5) << 3;
    int kq = wv;
    float16 acc;
#pragma unroll
    for (int r = 0; r < 16; r++) acc[r] = 0.f;
#pragma unroll
    for (int i = 0; i < 9; i++) {
        int ksg = kq * 9 + i;
        int tap = ksg >> 2;
        int c0 = ((ksg & 3) << 4) + half8;
        int ty = tap / 3, tx = tap - 3 * ty;
        int eb = ty * K2_RS + (m + tx) * K2_WS + c0;
        short4_t h0v = *(const short4_t*)(xh + eb);
        short4_t h1v = *(const short4_t*)(xh + eb + 4);
        short4_t l0v = *(const short4_t*)(xl + eb);
        short4_t l1v = *(const short4_t*)(xl + eb + 4);
        short8 ah, al;
        ah[0]=h0v[0]; ah[1]=h0v[1]; ah[2]=h0v[2]; ah[3]=h0v[3];
        ah[4]=h1v[0]; ah[5]=h1v[1]; ah[6]=h1v[2]; ah[7]=h1v[3];
        al[0]=l0v[0]; al[1]=l0v[1]; al[2]=l0v[2]; al[3]=l0v[3];
        al[4]=l1v[0]; al[5]=l1v[1]; al[6]=l1v[2]; al[7]=l1v[3];
        short8 bh = Woh[ksg * 64 + lane];
        short8 bl = Wol[ksg * 64 + lane];
        acc = __builtin_amdgcn_mfma_f32_32x32x16_bf16(ah, bh, acc, 0, 0, 0);
        acc = __builtin_amdgcn_mfma_f32_32x32x16_bf16(ah, bl, acc, 0, 0, 0);
        acc = __builtin_amdgcn_mfma_f32_32x32x16_bf16(al, bh, acc, 0, 0, 0);
    }
    __syncthreads();                 // all A-reads complete before obuf aliases xh/xl
    float* obuf = (float*)sstage;    // [4][32][33] fp32 = 16,896 B
#pragma unroll
    for (int r = 0; r < 16; r++) {
        int row = (r & 3) + 8 * (r >> 2) + 4 * (lane >> 5);
        obuf[(kq * 32 + row) * 33 + m] = acc[r];
    }
    __syncthreads();
    for (int t2 = t; t2 < 576; t2 += 256) {
        int p = (t2 * 3641) >> 16;      // /18
        int k = t2 - p * 18;
        float v = obuf[p * 33 + k] + obuf[(32 + p) * 33 + k]
                + obuf[(64 + p) * 33 + k] + obuf[(96 + p) * 33 + k];
        int ko = (k < 9) ? 2 * k : 2 * (k - 9) + 1;
        offs[(pixbase + p) * 18 + k] = v + b_off[ko];
    }
}

// ---------------------------------------------------------------- K3: sample + MFMA contraction
__global__ __launch_bounds__(256) void main_kernel(float* __restrict__ out,
                                                   const char* __restrict__ wsb) {
    const unsigned short* xpb = (const unsigned short*)(wsb + XPB_B);
    const float* offs = (const float*)(wsb + OFFS_B);
    const short8* Wb  = (const short8*)(wsb + WBB_B);
    __shared__ __attribute__((aligned(16))) char smem[47488];
    unsigned short* xs = (unsigned short*)smem;              // [32][XS_STRIDE] bf16 = 37,120 B
    int4*   cdatL = (int4*)(smem + 37120);                   // [288] corner BYTE offsets
    float4* cdatG = (float4*)(smem + 41728);                 // [288] bilinear weights
    int*    sAdr  = (int*)(smem + 46336);                    // [288] xs store byte offsets
    float*  obuf  = (float*)(smem + 37120);                  // [2][32][33] aliased (cdat dead)

    int t = threadIdx.x;
    int pixbase = blockIdx.x * 32;
    int w0 = pixbase & 127, h0 = (pixbase >> 7) & 127, bimg = pixbase >> 14;

    // ---- phase A: per-(pixel,tap) scalar bilinear setup (exact fp32, mirrors reference)
    for (int it = t; it < 288; it += 256) {
        int p = (it * 7282) >> 16;              // /9
        int n = it - p * 9;
        int pix = pixbase + p;
        float orow = offs[pix * 18 + n], ocol = offs[pix * 18 + 9 + n];
        float pr = (float)(h0 + (n / 3)) + orow;
        float pc = (float)(w0 + p + (n % 3)) + ocol;
        float flr = floorf(pr), flc = floorf(pc);
        float qlt_r = fminf(fmaxf(flr, 0.f), 129.f);
        float qlt_c = fminf(fmaxf(flc, 0.f), 129.f);
        float qrb_r = fminf(fmaxf(flr + 1.f, 0.f), 129.f);
        float qrb_c = fminf(fmaxf(flc + 1.f, 0.f), 129.f);
        bool mr = (pr < 1.f) || (pr > 128.f);
        bool mc = (pc < 1.f) || (pc > 128.f);
        float pr2 = mr ? flr : pr; pr2 = fminf(fmaxf(pr2, 0.f), 129.f);
        float pc2 = mc ? flc : pc; pc2 = fminf(fmaxf(pc2, 0.f), 129.f);
        float wr_lt = 1.f + (qlt_r - pr2);
        float wr_rb = 1.f - (qrb_r - pr2);
        float wc_lt = 1.f + (qlt_c - pc2);
        float wc_rb = 1.f - (qrb_c - pc2);
        int ilt_r = (int)qlt_r, ilt_c = (int)qlt_c;
        int irb_r = (int)qrb_r, irb_c = (int)qrb_c;
        cdatL[it] = make_int4((ilt_r * 130 + ilt_c) * 128, (irb_r * 130 + irb_c) * 128,
                              (ilt_r * 130 + irb_c) * 128, (irb_r * 130 + ilt_c) * 128);
        cdatG[it] = make_float4(wr_lt * wc_lt, wr_rb * wc_rb, wr_lt * wc_rb, wr_rb * wc_lt);
        sAdr[it]  = p * (XS_STRIDE * 2) + n * 128;
    }
    __syncthreads();

    // ---- phase B: gather (2 items/wave-load: 32 lanes x 2ch each = 256B lines)
    int lane = t & 63, wv = t >> 6;
    int half = lane >> 5;
    int cp4 = (lane & 31) * 4;
    const char* bp = (const char*)(xpb + bimg * (130 * 130 * 64));
    char* xsb = (char*)xs;
    int base = wv * 72;
#pragma unroll 4
    for (int i = 0; i < 36; i++) {
        int item = base + 2 * i + half;
        int4 L = cdatL[item];
        float4 G = cdatG[item];
        int sa = sAdr[item];
        unsigned int vlt = *(const unsigned int*)(bp + L.x + cp4);
        unsigned int vrb = *(const unsigned int*)(bp + L.y + cp4);
        unsigned int vlb = *(const unsigned int*)(bp + L.z + cp4);
        unsigned int vrt = *(const unsigned int*)(bp + L.w + cp4);
        float lo = fmaf(G.x, bflo2f(vlt), fmaf(G.y, bflo2f(vrb), fmaf(G.z, bflo2f(vlb), G.w * bflo2f(vrt))));
        float hi = fmaf(G.x, bfhi2f(vlt), fmaf(G.y, bfhi2f(vrb), fmaf(G.z, bfhi2f(vlb), G.w * bfhi2f(vrt))));
        __hip_bfloat162 pk2 = __float22bfloat162_rn(make_float2(lo, hi));   // lo -> low 16 bits
        *(unsigned int*)(xsb + sa + cp4) = *(unsigned int*)&pk2;
    }
    __syncthreads();

    // ---- phase C: MFMA. wave wv: nt = N-tile (32 outs), kh = K-half (288)
    int nt = wv & 1, kh = wv >> 1;
    float16 acc;
#pragma unroll
    for (int r = 0; r < 16; r++) acc[r] = 0.f;
    int m = lane & 31;
    for (int i2 = 0; i2 < 18; i2++) {
        int ksg = kh * 18 + i2;
        int baseE = m * XS_STRIDE + ksg * 16 + ((lane >> 5) << 3);
        short4_t a0 = *(const short4_t*)(xs + baseE);        // b64: stride 290dw -> 2-way only
        short4_t a1 = *(const short4_t*)(xs + baseE + 4);
        short8 af;
        af[0] = a0[0]; af[1] = a0[1]; af[2] = a0[2]; af[3] = a0[3];
        af[4] = a1[0]; af[5] = a1[1]; af[6] = a1[2]; af[7] = a1[3];
        short8 bfv = Wb[(nt * 36 + ksg) * 64 + lane];        // coalesced 1KB, L2-resident
        acc = __builtin_amdgcn_mfma_f32_32x32x16_bf16(af, bfv, acc, 0, 0, 0);
    }
    if (kh == 1) {
#pragma unroll
        for (int r = 0; r < 16; r++) {
            int mrow = (r & 3) + 8 * (r >> 2) + 4 * (lane >> 5);
            obuf[nt * 1056 + mrow * 33 + (lane & 31)] = acc[r];
        }
    }
    __syncthreads();
    if (kh == 0) {
#pragma unroll
        for (int r = 0; r < 16; r++) {
            int mrow = (r & 3) + 8 * (r >> 2) + 4 * (lane >> 5);
            int oi = nt * 1056 + mrow * 33 + (lane & 31);
            obuf[oi] = acc[r] + obuf[oi];
        }
    }
    __syncthreads();
#pragma unroll
    for (int i = 0; i < 8; i++) {
        int lin = i * 256 + t;
        int o = lin >> 5, p = lin & 31;
        float v = obuf[(o >> 5) * 1056 + p * 33 + (o & 31)];
        out[((bimg * 64 + o) << 14) + (h0 << 7) + w0 + p] = v;
    }
}

// ---------------------------------------------------------------- launch
extern "C" void kernel_launch(void* const* d_in, const int* in_sizes, int n_in,
                              void* d_out, int out_size, void* d_ws, size_t ws_size,
                              hipStream_t stream) {
    const float* x      = (const float*)d_in[0];
    const float* W_off  = (const float*)d_in[1];
    const float* b_off  = (const float*)d_in[2];
    const float* W_conv = (const float*)d_in[3];
    char* wsb  = (char*)d_ws;            // needs 22,171,648 B
    float* out = (float*)d_out;

    hipLaunchKernelGGL(pad_prep, dim3(536), dim3(256), 0, stream, x, W_off, W_conv, wsb);
    hipLaunchKernelGGL(offsets_mfma, dim3(NPIX / 32), dim3(256), 0, stream, b_off, wsb);
    hipLaunchKernelGGL(main_kernel, dim3(NPIX / 32), dim3(256), 0, stream, out, wsb);
}

// Round 4
// 134.676 us; speedup vs baseline: 2.4301x; 1.0443x over previous
//
#include <hip/hip_runtime.h>
#include <hip/hip_bf16.h>
#include <math.h>

// DeformConv2D MI355X: b=4,c=64,H=W=128,KS=3,N=9 -> out[b,o,h,w] = sum_{c,n} W[o,c,n]*bilin(xpad,p)
// R4: single fused kernel (offset-conv MFMA + bilinear gather + contraction MFMA) per 32-pixel
//     row block; offs stays in LDS (no global round-trip). 2 launches total.

typedef __attribute__((ext_vector_type(8)))  short short8;
typedef __attribute__((ext_vector_type(4)))  short short4_t;
typedef __attribute__((ext_vector_type(16))) float float16;

#define NPIX 65536
#define XS_STRIDE 580   // xs leading dim (bf16): dword stride 290 = 2 mod 32 -> 2-way (free)
#define K2_WS 68        // stage wp stride (64ch + 4 pad): byte stride 136 = 8*17 (b64-aligned)
#define K2_RS 2312      // stage row stride (34*68)

// workspace layout (byte offsets)
#define XPB_B   0u           // bf16 hi padded NHWC x : 4*130*130*64*2 = 8,652,800 B
#define XPL_B   8652800u     // bf16 lo residual      : 8,652,800 B
#define WBB_B   17305600u    // W_conv bf16 MFMA B-frags: 73,728 B
#define WOH_B   17379328u    // W_off hi B-frags      : 36,864 B
#define WOL_B   17416192u    // W_off lo B-frags      : 36,864 B   (end 17,453,056)

__device__ inline unsigned short f2bf(float f) {
    unsigned int u = __float_as_uint(f);
    u += 0x7fffu + ((u >> 16) & 1u);           // RNE
    return (unsigned short)(u >> 16);
}
__device__ inline float bfhi2f(unsigned int v) { return __uint_as_float(v & 0xffff0000u); }
__device__ inline float bflo2f(unsigned int v) { return __uint_as_float(v << 16); }

// ---------------------------------------------------------------- K1: pad/transpose + weight prep
__global__ __launch_bounds__(256) void pad_prep(const float* __restrict__ x,
                                                const float* __restrict__ W_off,
                                                const float* __restrict__ W_conv,
                                                char* __restrict__ wsb) {
    unsigned short* xpb = (unsigned short*)(wsb + XPB_B);
    unsigned short* xpl = (unsigned short*)(wsb + XPL_B);
    int t = threadIdx.x;
    if (blockIdx.x >= 520) {   // ---- weight prep: 16 blocks x 3456 items
        unsigned short* Wb  = (unsigned short*)(wsb + WBB_B);
        unsigned short* Woh = (unsigned short*)(wsb + WOH_B);
        unsigned short* Wol = (unsigned short*)(wsb + WOL_B);
        int wb = blockIdx.x - 520;
        for (int ii = t; ii < 3456; ii += 256) {
            int e = wb * 3456 + ii;
            if (e < 36864) {
                int j = e & 7, lane = (e >> 3) & 63, t2 = e >> 9;
                int ks = t2 % 36, nt = t2 / 36;
                int k = ks * 16 + ((lane >> 5) << 3) + j;
                int n = nt * 32 + (lane & 31);
                Wb[e] = f2bf(W_conv[(n * 64 + (k & 63)) * 9 + (k >> 6)]);
            } else {
                int e2 = e - 36864;     // W_off hi/lo frags, N=32 (18 used)
                int j = e2 & 7, lane = (e2 >> 3) & 63, ksg = e2 >> 9;
                int k = ksg * 16 + ((lane >> 5) << 3) + j;
                int c = k & 63, tap = k >> 6, n = lane & 31;
                float v = 0.f;
                if (n < 18) { int ko = (n < 9) ? 2 * n : 2 * (n - 9) + 1; v = W_off[(ko * 64 + c) * 9 + tap]; }
                unsigned short hi = f2bf(v);
                Woh[e2] = hi;
                Wol[e2] = f2bf(v - bfhi2f((unsigned int)hi << 16));
            }
        }
        return;
    }
    __shared__ float tile[64][129];
    int hp = blockIdx.x % 130, b = blockIdx.x / 130;
    int rowbase = ((b * 130 + hp) * 130) * 64;
    if (hp == 0 || hp == 129) {
        for (int i = t; i < 130 * 32; i += 256) {
            ((unsigned*)(xpb + rowbase))[i] = 0u;
            ((unsigned*)(xpl + rowbase))[i] = 0u;
        }
        return;
    }
    int h = hp - 1;
    {
        int w = t & 127, chalf = t >> 7;
        for (int cc = 0; cc < 64; cc += 2) {
            int c = cc + chalf;
            tile[c][w] = x[(((b * 64 + c) * 128) + h) * 128 + w];   // coalesced over w
        }
    }
    __syncthreads();
    {
        int c2 = (t & 31) * 2, wq = t >> 5;        // 2 channels/thread -> dword stores (256B/wave)
        if (wq == 0) { ((unsigned*)(xpb + rowbase))[t & 31] = 0u; ((unsigned*)(xpl + rowbase))[t & 31] = 0u; }
        if (wq == 1) { ((unsigned*)(xpb + rowbase + 129 * 64))[t & 31] = 0u; ((unsigned*)(xpl + rowbase + 129 * 64))[t & 31] = 0u; }
        for (int w = wq; w < 128; w += 8) {
            float v0 = tile[c2][w], v1 = tile[c2 + 1][w];
            unsigned short h0 = f2bf(v0), h1 = f2bf(v1);
            unsigned short l0 = f2bf(v0 - bfhi2f((unsigned int)h0 << 16));
            unsigned short l1 = f2bf(v1 - bfhi2f((unsigned int)h1 << 16));
            int ad = (rowbase + (w + 1) * 64) / 2 + (t & 31);
            ((unsigned*)xpb)[ad] = (unsigned)h0 | ((unsigned)h1 << 16);
            ((unsigned*)xpl)[ad] = (unsigned)l0 | ((unsigned)l1 << 16);
        }
    }
}

// ---------------------------------------------------------------- K2: fused deform-conv
// block = 256 thr (4 waves), 32 pixels (one row segment).
// P0 stage xh/xl 3x34x64 -> LDS. P1 offset MFMA (split-bf16, K/4 per wave). P2 obuf.
// P3/P4 bilinear setup (regs -> cdat, aliasing obuf). P5 gather -> xs (aliases stage).
// P6 contraction MFMA. P7 combine + store.
__global__ __launch_bounds__(256, 3) void fused_kernel(const float* __restrict__ b_off,
                                                       float* __restrict__ out,
                                                       char* __restrict__ wsb) {
    const unsigned* xpbw = (const unsigned*)(wsb + XPB_B);
    const unsigned* xplw = (const unsigned*)(wsb + XPL_B);
    const short8* Wb  = (const short8*)(wsb + WBB_B);
    const short8* Woh = (const short8*)(wsb + WOH_B);
    const short8* Wol = (const short8*)(wsb + WOL_B);

    __shared__ __attribute__((aligned(16))) char smem[46848];
    unsigned short* xh = (unsigned short*)smem;              // stage hi: 3*2312 elems (13,872B)
    unsigned short* xl = xh + 3 * K2_RS;                     // stage lo (ends 27,744B)
    unsigned short* xs = (unsigned short*)smem;              // [32][580] bf16 = 37,120B (after P1)
    float* obuf  = (float*)(smem + 37120);                   // [4][32][19] fp32 = 9,728B
    int4*   cdatL = (int4*)(smem + 37120);                   // [288] corner byte offsets (after P3)
    float4* cdatG = (float4*)(smem + 37120 + 4608);          // [288] bilinear weights
    float*  obuf2 = (float*)(smem + 37120);                  // [2][32][33] = 8,448B (after P5)

    int t = threadIdx.x;
    int lane = t & 63, wv = t >> 6;
    int pixbase = blockIdx.x * 32;
    int w0 = pixbase & 127, h0 = (pixbase >> 7) & 127, bimg = pixbase >> 14;

    // ---- P0: stage 3 rows x 34 cols x 64 ch hi/lo (dword = 2ch), fully coalesced
    for (int i = t; i < 3264; i += 256) {
        int row = i / 1088, rem = i - row * 1088;
        int wp = rem >> 5, cd = rem & 31;
        int g = ((bimg * 130 + h0 + row) * 130 + (w0 + wp)) * 32 + cd;
        int d = row * (K2_RS / 2) + wp * (K2_WS / 2) + cd;
        ((unsigned*)xh)[d] = xpbw[g];
        ((unsigned*)xl)[d] = xplw[g];
    }
    __syncthreads();                                         // B1

    // ---- P1: offset conv via split-bf16 MFMA (M=32 px, N=32 (18 used), K=576/4 per wave)
    int m = lane & 31, half8 = (lane >> 5) << 3;
    {
        float16 acc;
#pragma unroll
        for (int r = 0; r < 16; r++) acc[r] = 0.f;
#pragma unroll
        for (int i = 0; i < 9; i++) {
            int ksg = wv * 9 + i;
            int tap = ksg >> 2;
            int c0 = ((ksg & 3) << 4) + half8;
            int ty = tap / 3, tx = tap - 3 * ty;
            int eb = ty * K2_RS + (m + tx) * K2_WS + c0;
            short4_t h0v = *(const short4_t*)(xh + eb);
            short4_t h1v = *(const short4_t*)(xh + eb + 4);
            short4_t l0v = *(const short4_t*)(xl + eb);
            short4_t l1v = *(const short4_t*)(xl + eb + 4);
            short8 ah, al;
            ah[0]=h0v[0]; ah[1]=h0v[1]; ah[2]=h0v[2]; ah[3]=h0v[3];
            ah[4]=h1v[0]; ah[5]=h1v[1]; ah[6]=h1v[2]; ah[7]=h1v[3];
            al[0]=l0v[0]; al[1]=l0v[1]; al[2]=l0v[2]; al[3]=l0v[3];
            al[4]=l1v[0]; al[5]=l1v[1]; al[6]=l1v[2]; al[7]=l1v[3];
            short8 bh = Woh[ksg * 64 + lane];
            short8 bl = Wol[ksg * 64 + lane];
            acc = __builtin_amdgcn_mfma_f32_32x32x16_bf16(ah, bh, acc, 0, 0, 0);
            acc = __builtin_amdgcn_mfma_f32_32x32x16_bf16(ah, bl, acc, 0, 0, 0);
            acc = __builtin_amdgcn_mfma_f32_32x32x16_bf16(al, bh, acc, 0, 0, 0);
        }
        __syncthreads();                                     // B2: stage reads done, obuf fresh
        // ---- P2: partials -> obuf[wv][row][n] (n<18 used, stride 19)
        if (m < 18) {
#pragma unroll
            for (int r = 0; r < 16; r++) {
                int row = (r & 3) + 8 * (r >> 2) + 4 * (lane >> 5);
                obuf[(wv * 32 + row) * 19 + m] = acc[r];
            }
        }
    }
    __syncthreads();                                         // B3

    // ---- P3 (A1): per-(pixel,tap) bilinear setup into regs (exact fp32 decisions)
    int4   rL[2];
    float4 rG[2];
#pragma unroll
    for (int s = 0; s < 2; s++) {
        if (s == 1 && t >= 32) break;
        int it = t + s * 256;
        int p = (it * 7282) >> 16;              // /9
        int n = it - p * 9;
        float orow = b_off[2 * n], ocol = b_off[2 * n + 1];
#pragma unroll
        for (int kq = 0; kq < 4; kq++) {
            orow += obuf[(kq * 32 + p) * 19 + n];
            ocol += obuf[(kq * 32 + p) * 19 + 9 + n];
        }
        float pr = (float)(h0 + (n / 3)) + orow;
        float pc = (float)(w0 + p + (n % 3)) + ocol;
        float flr = floorf(pr), flc = floorf(pc);
        float qlt_r = fminf(fmaxf(flr, 0.f), 129.f);
        float qlt_c = fminf(fmaxf(flc, 0.f), 129.f);
        float qrb_r = fminf(fmaxf(flr + 1.f, 0.f), 129.f);
        float qrb_c = fminf(fmaxf(flc + 1.f, 0.f), 129.f);
        bool mr = (pr < 1.f) || (pr > 128.f);
        bool mc = (pc < 1.f) || (pc > 128.f);
        float pr2 = mr ? flr : pr; pr2 = fminf(fmaxf(pr2, 0.f), 129.f);
        float pc2 = mc ? flc : pc; pc2 = fminf(fmaxf(pc2, 0.f), 129.f);
        float wr_lt = 1.f + (qlt_r - pr2);
        float wr_rb = 1.f - (qrb_r - pr2);
        float wc_lt = 1.f + (qlt_c - pc2);
        float wc_rb = 1.f - (qrb_c - pc2);
        int ilt_r = (int)qlt_r, ilt_c = (int)qlt_c;
        int irb_r = (int)qrb_r, irb_c = (int)qrb_c;
        rL[s] = make_int4((ilt_r * 130 + ilt_c) * 128, (irb_r * 130 + irb_c) * 128,
                          (ilt_r * 130 + irb_c) * 128, (irb_r * 130 + ilt_c) * 128);
        rG[s] = make_float4(wr_lt * wc_lt, wr_rb * wc_rb, wr_lt * wc_rb, wr_rb * wc_lt);
    }
    __syncthreads();                                         // B4: obuf reads done
    // ---- P4 (A2): cdat writes (alias obuf)
#pragma unroll
    for (int s = 0; s < 2; s++) {
        if (s == 1 && t >= 32) break;
        cdatL[t + s * 256] = rL[s];
        cdatG[t + s * 256] = rG[s];
    }
    __syncthreads();                                         // B5

    // ---- P5: gather (2 items/wave-load, half-wave per item); xs aliases stage (reads done @B2)
    {
        int half = lane >> 5;
        int cp4 = (lane & 31) * 4;
        const char* bp = (const char*)(wsb + XPB_B) + (size_t)bimg * (130 * 130 * 128);
        char* xsb = (char*)xs;
        int n5 = half;                       // item = wv*72 + 2i + half -> p,n incremental
        int sa = wv * 8 * (XS_STRIDE * 2) + n5 * 128;
        int base = wv * 72;
#pragma unroll 4
        for (int i = 0; i < 36; i++) {
            int item = base + 2 * i + half;
            int4 L = cdatL[item];
            float4 G = cdatG[item];
            unsigned int vlt = *(const unsigned int*)(bp + L.x + cp4);
            unsigned int vrb = *(const unsigned int*)(bp + L.y + cp4);
            unsigned int vlb = *(const unsigned int*)(bp + L.z + cp4);
            unsigned int vrt = *(const unsigned int*)(bp + L.w + cp4);
            float lo = fmaf(G.x, bflo2f(vlt), fmaf(G.y, bflo2f(vrb), fmaf(G.z, bflo2f(vlb), G.w * bflo2f(vrt))));
            float hi = fmaf(G.x, bfhi2f(vlt), fmaf(G.y, bfhi2f(vrb), fmaf(G.z, bfhi2f(vlb), G.w * bfhi2f(vrt))));
            __hip_bfloat162 pk2 = __float22bfloat162_rn(make_float2(lo, hi));
            *(unsigned int*)(xsb + sa + cp4) = *(unsigned int*)&pk2;
            n5 += 2; sa += 256;
            if (n5 >= 9) { n5 -= 9; sa += 8; }   // (p+1, n-9): +1160 - 9*128 net vs +256
        }
    }
    __syncthreads();                                         // B6

    // ---- P6: contraction MFMA. wave: nt = N-tile (32 outs), kh = K-half (288)
    int nt = wv & 1, kh = wv >> 1;
    float16 acc;
#pragma unroll
    for (int r = 0; r < 16; r++) acc[r] = 0.f;
    for (int i2 = 0; i2 < 18; i2++) {
        int ksg = kh * 18 + i2;
        int baseE = m * XS_STRIDE + ksg * 16 + half8;
        short4_t a0 = *(const short4_t*)(xs + baseE);        // b64: stride 290dw -> 2-way only
        short4_t a1 = *(const short4_t*)(xs + baseE + 4);
        short8 af;
        af[0] = a0[0]; af[1] = a0[1]; af[2] = a0[2]; af[3] = a0[3];
        af[4] = a1[0]; af[5] = a1[1]; af[6] = a1[2]; af[7] = a1[3];
        short8 bfv = Wb[(nt * 36 + ksg) * 64 + lane];        // coalesced 1KB, L2-resident
        acc = __builtin_amdgcn_mfma_f32_32x32x16_bf16(af, bfv, acc, 0, 0, 0);
    }
    // ---- P7: K-half combine (obuf2 aliases cdat; cdat reads done @B6) + store
    if (kh == 1) {
#pragma unroll
        for (int r = 0; r < 16; r++) {
            int mrow = (r & 3) + 8 * (r >> 2) + 4 * (lane >> 5);
            obuf2[nt * 1056 + mrow * 33 + m] = acc[r];
        }
    }
    __syncthreads();                                         // B7
    if (kh == 0) {
#pragma unroll
        for (int r = 0; r < 16; r++) {
            int mrow = (r & 3) + 8 * (r >> 2) + 4 * (lane >> 5);
            int oi = nt * 1056 + mrow * 33 + m;
            obuf2[oi] = acc[r] + obuf2[oi];
        }
    }
    __syncthreads();                                         // B8
#pragma unroll
    for (int i = 0; i < 8; i++) {
        int lin = i * 256 + t;
        int o = lin >> 5, p = lin & 31;
        float v = obuf2[(o >> 5) * 1056 + p * 33 + (o & 31)];
        out[((bimg * 64 + o) << 14) + (h0 << 7) + w0 + p] = v;
    }
}

// ---------------------------------------------------------------- launch
extern "C" void kernel_launch(void* const* d_in, const int* in_sizes, int n_in,
                              void* d_out, int out_size, void* d_ws, size_t ws_size,
                              hipStream_t stream) {
    const float* x      = (const float*)d_in[0];
    const float* W_off  = (const float*)d_in[1];
    const float* b_off  = (const float*)d_in[2];
    const float* W_conv = (const float*)d_in[3];
    char* wsb  = (char*)d_ws;            // needs 17,453,056 B
    float* out = (float*)d_out;

    hipLaunchKernelGGL(pad_prep, dim3(536), dim3(256), 0, stream, x, W_off, W_conv, wsb);
    hipLaunchKernelGGL(fused_kernel, dim3(NPIX / 32), dim3(256), 0, stream, b_off, out, wsb);
}

// Round 5
// 132.847 us; speedup vs baseline: 2.4636x; 1.0138x over previous
//
#include <hip/hip_runtime.h>
#include <hip/hip_bf16.h>
#include <math.h>

// DeformConv2D MI355X: b=4,c=64,H=W=128,KS=3,N=9 -> out[b,o,h,w] = sum_{c,n} W[o,c,n]*bilin(xpad,p)
// R5: pad_prep at 1024 thr/block (32 waves/CU vs 8 - it was the hidden ~50us latency-bound cost);
//     fused kernel: shufflevector frag assembly, deeper gather unroll. Numerics identical to R4.

typedef __attribute__((ext_vector_type(8)))  short short8;
typedef __attribute__((ext_vector_type(4)))  short short4_t;
typedef __attribute__((ext_vector_type(16))) float float16;

#define NPIX 65536
#define XS_STRIDE 580   // xs leading dim (bf16): dword stride 290 = 2 mod 32 -> 2-way (free)
#define K2_WS 68        // stage wp stride (64ch + 4 pad): byte stride 136 (8B-aligned)
#define K2_RS 2312      // stage row stride (34*68)

// workspace layout (byte offsets)
#define XPB_B   0u           // bf16 hi padded NHWC x : 4*130*130*64*2 = 8,652,800 B
#define XPL_B   8652800u     // bf16 lo residual      : 8,652,800 B
#define WBB_B   17305600u    // W_conv bf16 MFMA B-frags: 73,728 B
#define WOH_B   17379328u    // W_off hi B-frags      : 36,864 B
#define WOL_B   17416192u    // W_off lo B-frags      : 36,864 B   (end 17,453,056)

__device__ inline unsigned short f2bf(float f) {
    unsigned int u = __float_as_uint(f);
    u += 0x7fffu + ((u >> 16) & 1u);           // RNE
    return (unsigned short)(u >> 16);
}
__device__ inline float bfhi2f(unsigned int v) { return __uint_as_float(v & 0xffff0000u); }
__device__ inline float bflo2f(unsigned int v) { return __uint_as_float(v << 16); }

// ---------------------------------------------------------------- K1: pad/transpose + weight prep
// 1024 threads/block. blocks 0..519: pad one (b,hp) row. blocks 520..535: weight fragments.
__global__ __launch_bounds__(1024) void pad_prep(const float* __restrict__ x,
                                                 const float* __restrict__ W_off,
                                                 const float* __restrict__ W_conv,
                                                 char* __restrict__ wsb) {
    unsigned short* xpb = (unsigned short*)(wsb + XPB_B);
    unsigned short* xpl = (unsigned short*)(wsb + XPL_B);
    int t = threadIdx.x;
    if (blockIdx.x >= 520) {   // ---- weight prep: 16 blocks x 3456 items
        unsigned short* Wb  = (unsigned short*)(wsb + WBB_B);
        unsigned short* Woh = (unsigned short*)(wsb + WOH_B);
        unsigned short* Wol = (unsigned short*)(wsb + WOL_B);
        int wb = blockIdx.x - 520;
        for (int ii = t; ii < 3456; ii += 1024) {
            int e = wb * 3456 + ii;
            if (e < 36864) {
                int j = e & 7, lane = (e >> 3) & 63, t2 = e >> 9;
                int ks = t2 % 36, nt = t2 / 36;
                int k = ks * 16 + ((lane >> 5) << 3) + j;
                int n = nt * 32 + (lane & 31);
                Wb[e] = f2bf(W_conv[(n * 64 + (k & 63)) * 9 + (k >> 6)]);
            } else {
                int e2 = e - 36864;     // W_off hi/lo frags, N=32 (18 used)
                int j = e2 & 7, lane = (e2 >> 3) & 63, ksg = e2 >> 9;
                int k = ksg * 16 + ((lane >> 5) << 3) + j;
                int c = k & 63, tap = k >> 6, n = lane & 31;
                float v = 0.f;
                if (n < 18) { int ko = (n < 9) ? 2 * n : 2 * (n - 9) + 1; v = W_off[(ko * 64 + c) * 9 + tap]; }
                unsigned short hi = f2bf(v);
                Woh[e2] = hi;
                Wol[e2] = f2bf(v - bfhi2f((unsigned int)hi << 16));
            }
        }
        return;
    }
    __shared__ float tile[64][129];
    int hp = blockIdx.x % 130, b = blockIdx.x / 130;
    int rowbase = ((b * 130 + hp) * 130) * 64;
    if (hp == 0 || hp == 129) {
        for (int i = t; i < 130 * 32; i += 1024) {
            ((unsigned*)(xpb + rowbase))[i] = 0u;
            ((unsigned*)(xpl + rowbase))[i] = 0u;
        }
        return;
    }
    int h = hp - 1;
    {
        int w = t & 127, cq = t >> 7;          // cq in 0..7
#pragma unroll
        for (int cc = 0; cc < 8; cc++) {
            int c = cq + cc * 8;
            tile[c][w] = x[(((b * 64 + c) * 128) + h) * 128 + w];   // coalesced over w
        }
    }
    __syncthreads();
    {
        int c2 = (t & 31) * 2, wq = t >> 5;    // wq in 0..31; 2 channels/thread -> dword stores
        if (wq == 0) { ((unsigned*)(xpb + rowbase))[t & 31] = 0u; ((unsigned*)(xpl + rowbase))[t & 31] = 0u; }
        if (wq == 1) { ((unsigned*)(xpb + rowbase + 129 * 64))[t & 31] = 0u; ((unsigned*)(xpl + rowbase + 129 * 64))[t & 31] = 0u; }
#pragma unroll
        for (int w = wq; w < 128; w += 32) {
            float v0 = tile[c2][w], v1 = tile[c2 + 1][w];
            unsigned short h0 = f2bf(v0), h1 = f2bf(v1);
            unsigned short l0 = f2bf(v0 - bfhi2f((unsigned int)h0 << 16));
            unsigned short l1 = f2bf(v1 - bfhi2f((unsigned int)h1 << 16));
            int ad = (rowbase + (w + 1) * 64) / 2 + (t & 31);
            ((unsigned*)xpb)[ad] = (unsigned)h0 | ((unsigned)h1 << 16);
            ((unsigned*)xpl)[ad] = (unsigned)l0 | ((unsigned)l1 << 16);
        }
    }
}

// ---------------------------------------------------------------- K2: fused deform-conv
// block = 256 thr (4 waves), 32 pixels (one row segment).
// P0 stage xh/xl 3x34x64 -> LDS. P1 offset MFMA (split-bf16, K/4 per wave). P2 obuf.
// P3/P4 bilinear setup (regs -> cdat, aliasing obuf). P5 gather -> xs (aliases stage).
// P6 contraction MFMA. P7 combine + store.
__global__ __launch_bounds__(256, 3) void fused_kernel(const float* __restrict__ b_off,
                                                       float* __restrict__ out,
                                                       char* __restrict__ wsb) {
    const unsigned* xpbw = (const unsigned*)(wsb + XPB_B);
    const unsigned* xplw = (const unsigned*)(wsb + XPL_B);
    const short8* Wb  = (const short8*)(wsb + WBB_B);
    const short8* Woh = (const short8*)(wsb + WOH_B);
    const short8* Wol = (const short8*)(wsb + WOL_B);

    __shared__ __attribute__((aligned(16))) char smem[46848];
    unsigned short* xh = (unsigned short*)smem;              // stage hi: 3*2312 elems (13,872B)
    unsigned short* xl = xh + 3 * K2_RS;                     // stage lo (ends 27,744B)
    unsigned short* xs = (unsigned short*)smem;              // [32][580] bf16 = 37,120B (after P1)
    float* obuf  = (float*)(smem + 37120);                   // [4][32][19] fp32 = 9,728B
    int4*   cdatL = (int4*)(smem + 37120);                   // [288] corner byte offsets (after P3)
    float4* cdatG = (float4*)(smem + 37120 + 4608);          // [288] bilinear weights
    float*  obuf2 = (float*)(smem + 37120);                  // [2][32][33] = 8,448B (after P5)

    int t = threadIdx.x;
    int lane = t & 63, wv = t >> 6;
    int pixbase = blockIdx.x * 32;
    int w0 = pixbase & 127, h0 = (pixbase >> 7) & 127, bimg = pixbase >> 14;

    // ---- P0: stage 3 rows x 34 cols x 64 ch hi/lo (dword = 2ch), fully coalesced
    for (int i = t; i < 3264; i += 256) {
        int row = i / 1088, rem = i - row * 1088;
        int wp = rem >> 5, cd = rem & 31;
        int g = ((bimg * 130 + h0 + row) * 130 + (w0 + wp)) * 32 + cd;
        int d = row * (K2_RS / 2) + wp * (K2_WS / 2) + cd;
        ((unsigned*)xh)[d] = xpbw[g];
        ((unsigned*)xl)[d] = xplw[g];
    }
    __syncthreads();                                         // B1

    // ---- P1: offset conv via split-bf16 MFMA (M=32 px, N=32 (18 used), K=576/4 per wave)
    int m = lane & 31, half8 = (lane >> 5) << 3;
    {
        float16 acc;
#pragma unroll
        for (int r = 0; r < 16; r++) acc[r] = 0.f;
#pragma unroll
        for (int i = 0; i < 9; i++) {
            int ksg = wv * 9 + i;
            int tap = ksg >> 2;
            int c0 = ((ksg & 3) << 4) + half8;
            int ty = tap / 3, tx = tap - 3 * ty;
            int eb = ty * K2_RS + (m + tx) * K2_WS + c0;
            short4_t h0v = *(const short4_t*)(xh + eb);
            short4_t h1v = *(const short4_t*)(xh + eb + 4);
            short4_t l0v = *(const short4_t*)(xl + eb);
            short4_t l1v = *(const short4_t*)(xl + eb + 4);
            short8 ah = __builtin_shufflevector(h0v, h1v, 0, 1, 2, 3, 4, 5, 6, 7);
            short8 al = __builtin_shufflevector(l0v, l1v, 0, 1, 2, 3, 4, 5, 6, 7);
            short8 bh = Woh[ksg * 64 + lane];
            short8 bl = Wol[ksg * 64 + lane];
            acc = __builtin_amdgcn_mfma_f32_32x32x16_bf16(ah, bh, acc, 0, 0, 0);
            acc = __builtin_amdgcn_mfma_f32_32x32x16_bf16(ah, bl, acc, 0, 0, 0);
            acc = __builtin_amdgcn_mfma_f32_32x32x16_bf16(al, bh, acc, 0, 0, 0);
        }
        __syncthreads();                                     // B2: stage reads done, obuf fresh
        // ---- P2: partials -> obuf[wv][row][n] (n<18 used, stride 19)
        if (m < 18) {
#pragma unroll
            for (int r = 0; r < 16; r++) {
                int row = (r & 3) + 8 * (r >> 2) + 4 * (lane >> 5);
                obuf[(wv * 32 + row) * 19 + m] = acc[r];
            }
        }
    }
    __syncthreads();                                         // B3

    // ---- P3 (A1): per-(pixel,tap) bilinear setup into regs (exact fp32 decisions)
    int4   rL[2];
    float4 rG[2];
#pragma unroll
    for (int s = 0; s < 2; s++) {
        if (s == 1 && t >= 32) break;
        int it = t + s * 256;
        int p = (it * 7282) >> 16;              // /9
        int n = it - p * 9;
        float orow = b_off[2 * n], ocol = b_off[2 * n + 1];
#pragma unroll
        for (int kq = 0; kq < 4; kq++) {
            orow += obuf[(kq * 32 + p) * 19 + n];
            ocol += obuf[(kq * 32 + p) * 19 + 9 + n];
        }
        float pr = (float)(h0 + (n / 3)) + orow;
        float pc = (float)(w0 + p + (n % 3)) + ocol;
        float flr = floorf(pr), flc = floorf(pc);
        float qlt_r = fminf(fmaxf(flr, 0.f), 129.f);
        float qlt_c = fminf(fmaxf(flc, 0.f), 129.f);
        float qrb_r = fminf(fmaxf(flr + 1.f, 0.f), 129.f);
        float qrb_c = fminf(fmaxf(flc + 1.f, 0.f), 129.f);
        bool mr = (pr < 1.f) || (pr > 128.f);
        bool mc = (pc < 1.f) || (pc > 128.f);
        float pr2 = mr ? flr : pr; pr2 = fminf(fmaxf(pr2, 0.f), 129.f);
        float pc2 = mc ? flc : pc; pc2 = fminf(fmaxf(pc2, 0.f), 129.f);
        float wr_lt = 1.f + (qlt_r - pr2);
        float wr_rb = 1.f - (qrb_r - pr2);
        float wc_lt = 1.f + (qlt_c - pc2);
        float wc_rb = 1.f - (qrb_c - pc2);
        int ilt_r = (int)qlt_r, ilt_c = (int)qlt_c;
        int irb_r = (int)qrb_r, irb_c = (int)qrb_c;
        rL[s] = make_int4((ilt_r * 130 + ilt_c) * 128, (irb_r * 130 + irb_c) * 128,
                          (ilt_r * 130 + irb_c) * 128, (irb_r * 130 + ilt_c) * 128);
        rG[s] = make_float4(wr_lt * wc_lt, wr_rb * wc_rb, wr_lt * wc_rb, wr_rb * wc_lt);
    }
    __syncthreads();                                         // B4: obuf reads done
    // ---- P4 (A2): cdat writes (alias obuf)
#pragma unroll
    for (int s = 0; s < 2; s++) {
        if (s == 1 && t >= 32) break;
        cdatL[t + s * 256] = rL[s];
        cdatG[t + s * 256] = rG[s];
    }
    __syncthreads();                                         // B5

    // ---- P5: gather (2 items/wave-load, half-wave per item); xs aliases stage (reads done @B2)
    {
        int half = lane >> 5;
        int cp4 = (lane & 31) * 4;
        const char* bp = (const char*)(wsb + XPB_B) + (size_t)bimg * (130 * 130 * 128);
        char* xsb = (char*)xs;
        int n5 = half;                       // item = wv*72 + 2i + half -> p,n incremental
        int sa = wv * 8 * (XS_STRIDE * 2) + n5 * 128;
        int base = wv * 72;
#pragma unroll 6
        for (int i = 0; i < 36; i++) {
            int item = base + 2 * i + half;
            int4 L = cdatL[item];
            float4 G = cdatG[item];
            unsigned int vlt = *(const unsigned int*)(bp + L.x + cp4);
            unsigned int vrb = *(const unsigned int*)(bp + L.y + cp4);
            unsigned int vlb = *(const unsigned int*)(bp + L.z + cp4);
            unsigned int vrt = *(const unsigned int*)(bp + L.w + cp4);
            float lo = fmaf(G.x, bflo2f(vlt), fmaf(G.y, bflo2f(vrb), fmaf(G.z, bflo2f(vlb), G.w * bflo2f(vrt))));
            float hi = fmaf(G.x, bfhi2f(vlt), fmaf(G.y, bfhi2f(vrb), fmaf(G.z, bfhi2f(vlb), G.w * bfhi2f(vrt))));
            __hip_bfloat162 pk2 = __float22bfloat162_rn(make_float2(lo, hi));
            *(unsigned int*)(xsb + sa + cp4) = *(unsigned int*)&pk2;
            n5 += 2; sa += 256;
            if (n5 >= 9) { n5 -= 9; sa += 8; }   // (p+1, n-9): net vs +256
        }
    }
    __syncthreads();                                         // B6

    // ---- P6: contraction MFMA. wave: nt = N-tile (32 outs), kh = K-half (288)
    int nt = wv & 1, kh = wv >> 1;
    float16 acc;
#pragma unroll
    for (int r = 0; r < 16; r++) acc[r] = 0.f;
    for (int i2 = 0; i2 < 18; i2++) {
        int ksg = kh * 18 + i2;
        int baseE = m * XS_STRIDE + ksg * 16 + half8;
        short4_t a0 = *(const short4_t*)(xs + baseE);        // b64: stride 290dw -> 2-way only
        short4_t a1 = *(const short4_t*)(xs + baseE + 4);
        short8 af = __builtin_shufflevector(a0, a1, 0, 1, 2, 3, 4, 5, 6, 7);
        short8 bfv = Wb[(nt * 36 + ksg) * 64 + lane];        // coalesced 1KB, L2-resident
        acc = __builtin_amdgcn_mfma_f32_32x32x16_bf16(af, bfv, acc, 0, 0, 0);
    }
    // ---- P7: K-half combine (obuf2 aliases cdat; cdat reads done @B6) + store
    if (kh == 1) {
#pragma unroll
        for (int r = 0; r < 16; r++) {
            int mrow = (r & 3) + 8 * (r >> 2) + 4 * (lane >> 5);
            obuf2[nt * 1056 + mrow * 33 + m] = acc[r];
        }
    }
    __syncthreads();                                         // B7
    if (kh == 0) {
#pragma unroll
        for (int r = 0; r < 16; r++) {
            int mrow = (r & 3) + 8 * (r >> 2) + 4 * (lane >> 5);
            int oi = nt * 1056 + mrow * 33 + m;
            obuf2[oi] = acc[r] + obuf2[oi];
        }
    }
    __syncthreads();                                         // B8
#pragma unroll
    for (int i = 0; i < 8; i++) {
        int lin = i * 256 + t;
        int o = lin >> 5, p = lin & 31;
        float v = obuf2[(o >> 5) * 1056 + p * 33 + (o & 31)];
        out[((bimg * 64 + o) << 14) + (h0 << 7) + w0 + p] = v;
    }
}

// ---------------------------------------------------------------- launch
extern "C" void kernel_launch(void* const* d_in, const int* in_sizes, int n_in,
                              void* d_out, int out_size, void* d_ws, size_t ws_size,
                              hipStream_t stream) {
    const float* x      = (const float*)d_in[0];
    const float* W_off  = (const float*)d_in[1];
    const float* b_off  = (const float*)d_in[2];
    const float* W_conv = (const float*)d_in[3];
    char* wsb  = (char*)d_ws;            // needs 17,453,056 B
    float* out = (float*)d_out;

    hipLaunchKernelGGL(pad_prep, dim3(536), dim3(1024), 0, stream, x, W_off, W_conv, wsb);
    hipLaunchKernelGGL(fused_kernel, dim3(NPIX / 32), dim3(256), 0, stream, b_off, out, wsb);
}

// Round 6
// 128.812 us; speedup vs baseline: 2.5407x; 1.0313x over previous
//
#include <hip/hip_runtime.h>
#include <hip/hip_bf16.h>
#include <math.h>

// DeformConv2D MI355X: b=4,c=64,H=W=128,KS=3,N=9 -> out[b,o,h,w] = sum_{c,n} W[o,c,n]*bilin(xpad,p)
// R6: split fused kernel into K2a (offset MFMA + bilinear setup -> global cdat, LDS 27.7KB,
//     5 blk/CU) and K2b (gather + contraction MFMA, LDS 37.1KB, 4 blk/CU). Both ~2x resident
//     waves vs R5 monolith; fewer barriers per kernel. Numerics bit-identical to R5.

typedef __attribute__((ext_vector_type(8)))  short short8;
typedef __attribute__((ext_vector_type(4)))  short short4_t;
typedef __attribute__((ext_vector_type(16))) float float16;

#define NPIX 65536
#define XS_STRIDE 580   // xs leading dim (bf16): dword stride 290 = 2 mod 32 -> 2-way (free)
#define K2_WS 68        // stage wp stride (64ch + 4 pad)
#define K2_RS 2312      // stage row stride (34*68)

// workspace layout (byte offsets)
#define XPB_B   0u           // bf16 hi padded NHWC x : 8,652,800 B
#define XPL_B   8652800u     // bf16 lo residual      : 8,652,800 B
#define WBB_B   17305600u    // W_conv bf16 MFMA B-frags: 73,728 B
#define WOH_B   17379328u    // W_off hi B-frags      : 36,864 B
#define WOL_B   17416192u    // W_off lo B-frags      : 36,864 B
#define CPK_B   17453056u    // packed corner coords  : 2048*288*4  = 2,359,296 B
#define CWT_B   19812352u    // factor weights float4 : 2048*288*16 = 9,437,184 B (end 29,249,536)

__device__ inline unsigned short f2bf(float f) {
    unsigned int u = __float_as_uint(f);
    u += 0x7fffu + ((u >> 16) & 1u);           // RNE
    return (unsigned short)(u >> 16);
}
__device__ inline float bfhi2f(unsigned int v) { return __uint_as_float(v & 0xffff0000u); }
__device__ inline float bflo2f(unsigned int v) { return __uint_as_float(v << 16); }

// ---------------------------------------------------------------- K1: pad/transpose + weight prep
__global__ __launch_bounds__(1024) void pad_prep(const float* __restrict__ x,
                                                 const float* __restrict__ W_off,
                                                 const float* __restrict__ W_conv,
                                                 char* __restrict__ wsb) {
    unsigned short* xpb = (unsigned short*)(wsb + XPB_B);
    unsigned short* xpl = (unsigned short*)(wsb + XPL_B);
    int t = threadIdx.x;
    if (blockIdx.x >= 520) {   // ---- weight prep: 16 blocks x 3456 items
        unsigned short* Wb  = (unsigned short*)(wsb + WBB_B);
        unsigned short* Woh = (unsigned short*)(wsb + WOH_B);
        unsigned short* Wol = (unsigned short*)(wsb + WOL_B);
        int wb = blockIdx.x - 520;
        for (int ii = t; ii < 3456; ii += 1024) {
            int e = wb * 3456 + ii;
            if (e < 36864) {
                int j = e & 7, lane = (e >> 3) & 63, t2 = e >> 9;
                int ks = t2 % 36, nt = t2 / 36;
                int k = ks * 16 + ((lane >> 5) << 3) + j;
                int n = nt * 32 + (lane & 31);
                Wb[e] = f2bf(W_conv[(n * 64 + (k & 63)) * 9 + (k >> 6)]);
            } else {
                int e2 = e - 36864;     // W_off hi/lo frags, N=32 (18 used)
                int j = e2 & 7, lane = (e2 >> 3) & 63, ksg = e2 >> 9;
                int k = ksg * 16 + ((lane >> 5) << 3) + j;
                int c = k & 63, tap = k >> 6, n = lane & 31;
                float v = 0.f;
                if (n < 18) { int ko = (n < 9) ? 2 * n : 2 * (n - 9) + 1; v = W_off[(ko * 64 + c) * 9 + tap]; }
                unsigned short hi = f2bf(v);
                Woh[e2] = hi;
                Wol[e2] = f2bf(v - bfhi2f((unsigned int)hi << 16));
            }
        }
        return;
    }
    __shared__ float tile[64][129];
    int hp = blockIdx.x % 130, b = blockIdx.x / 130;
    int rowbase = ((b * 130 + hp) * 130) * 64;
    if (hp == 0 || hp == 129) {
        for (int i = t; i < 130 * 32; i += 1024) {
            ((unsigned*)(xpb + rowbase))[i] = 0u;
            ((unsigned*)(xpl + rowbase))[i] = 0u;
        }
        return;
    }
    int h = hp - 1;
    {
        int w = t & 127, cq = t >> 7;
#pragma unroll
        for (int cc = 0; cc < 8; cc++) {
            int c = cq + cc * 8;
            tile[c][w] = x[(((b * 64 + c) * 128) + h) * 128 + w];   // coalesced over w
        }
    }
    __syncthreads();
    {
        int c2 = (t & 31) * 2, wq = t >> 5;
        if (wq == 0) { ((unsigned*)(xpb + rowbase))[t & 31] = 0u; ((unsigned*)(xpl + rowbase))[t & 31] = 0u; }
        if (wq == 1) { ((unsigned*)(xpb + rowbase + 129 * 64))[t & 31] = 0u; ((unsigned*)(xpl + rowbase + 129 * 64))[t & 31] = 0u; }
#pragma unroll
        for (int w = wq; w < 128; w += 32) {
            float v0 = tile[c2][w], v1 = tile[c2 + 1][w];
            unsigned short h0 = f2bf(v0), h1 = f2bf(v1);
            unsigned short l0 = f2bf(v0 - bfhi2f((unsigned int)h0 << 16));
            unsigned short l1 = f2bf(v1 - bfhi2f((unsigned int)h1 << 16));
            int ad = (rowbase + (w + 1) * 64) / 2 + (t & 31);
            ((unsigned*)xpb)[ad] = (unsigned)h0 | ((unsigned)h1 << 16);
            ((unsigned*)xpl)[ad] = (unsigned)l0 | ((unsigned)l1 << 16);
        }
    }
}

// ---------------------------------------------------------------- K2a: offset conv + bilinear setup
// block = 256 thr (4 waves), 32 pixels. Stage 3x34x64 hi/lo -> 27 split-bf16 MFMA -> obuf
// (aliases stage) -> per-item packed corners + factor weights to GLOBAL. LDS 27,744 B.
__global__ __launch_bounds__(256) void offset_setup(const float* __restrict__ b_off,
                                                    char* __restrict__ wsb) {
    const unsigned* xpbw = (const unsigned*)(wsb + XPB_B);
    const unsigned* xplw = (const unsigned*)(wsb + XPL_B);
    const short8* Woh = (const short8*)(wsb + WOH_B);
    const short8* Wol = (const short8*)(wsb + WOL_B);
    unsigned* cpkG = (unsigned*)(wsb + CPK_B);
    float4*   cwtG = (float4*)(wsb + CWT_B);

    __shared__ __attribute__((aligned(16))) char smem[27744];
    unsigned short* xh = (unsigned short*)smem;              // stage hi: 3*2312 (13,872 B)
    unsigned short* xl = xh + 3 * K2_RS;                     // stage lo
    float* obuf = (float*)smem;                              // [4][32][19] = 9,728 B (after B2)

    int t = threadIdx.x;
    int lane = t & 63, wv = t >> 6;
    int pixbase = blockIdx.x * 32;
    int w0 = pixbase & 127, h0 = (pixbase >> 7) & 127, bimg = pixbase >> 14;

    // ---- P0: stage 3 rows x 34 cols x 64 ch hi/lo (dword = 2ch), fully coalesced
    for (int i = t; i < 3264; i += 256) {
        int row = i / 1088, rem = i - row * 1088;
        int wp = rem >> 5, cd = rem & 31;
        int g = ((bimg * 130 + h0 + row) * 130 + (w0 + wp)) * 32 + cd;
        int d = row * (K2_RS / 2) + wp * (K2_WS / 2) + cd;
        ((unsigned*)xh)[d] = xpbw[g];
        ((unsigned*)xl)[d] = xplw[g];
    }
    __syncthreads();                                         // B1

    // ---- P1: offset conv via split-bf16 MFMA (M=32 px, N=32 (18 used), K=576/4 per wave)
    int m = lane & 31, half8 = (lane >> 5) << 3;
    float16 acc;
#pragma unroll
    for (int r = 0; r < 16; r++) acc[r] = 0.f;
#pragma unroll
    for (int i = 0; i < 9; i++) {
        int ksg = wv * 9 + i;
        int tap = ksg >> 2;
        int c0 = ((ksg & 3) << 4) + half8;
        int ty = tap / 3, tx = tap - 3 * ty;
        int eb = ty * K2_RS + (m + tx) * K2_WS + c0;
        short4_t h0v = *(const short4_t*)(xh + eb);
        short4_t h1v = *(const short4_t*)(xh + eb + 4);
        short4_t l0v = *(const short4_t*)(xl + eb);
        short4_t l1v = *(const short4_t*)(xl + eb + 4);
        short8 ah = __builtin_shufflevector(h0v, h1v, 0, 1, 2, 3, 4, 5, 6, 7);
        short8 al = __builtin_shufflevector(l0v, l1v, 0, 1, 2, 3, 4, 5, 6, 7);
        short8 bh = Woh[ksg * 64 + lane];
        short8 bl = Wol[ksg * 64 + lane];
        acc = __builtin_amdgcn_mfma_f32_32x32x16_bf16(ah, bh, acc, 0, 0, 0);
        acc = __builtin_amdgcn_mfma_f32_32x32x16_bf16(ah, bl, acc, 0, 0, 0);
        acc = __builtin_amdgcn_mfma_f32_32x32x16_bf16(al, bh, acc, 0, 0, 0);
    }
    __syncthreads();                                         // B2: stage reads done, obuf fresh
    // ---- P2: partials -> obuf[wv][row][n] (n<18 used, stride 19)
    if (m < 18) {
#pragma unroll
        for (int r = 0; r < 16; r++) {
            int row = (r & 3) + 8 * (r >> 2) + 4 * (lane >> 5);
            obuf[(wv * 32 + row) * 19 + m] = acc[r];
        }
    }
    __syncthreads();                                         // B3

    // ---- P3: per-(pixel,tap) bilinear setup (exact fp32 decisions) -> global cdat
    int gbase = blockIdx.x * 288;
#pragma unroll
    for (int s = 0; s < 2; s++) {
        if (s == 1 && t >= 32) break;
        int it = t + s * 256;
        int p = (it * 7282) >> 16;              // /9
        int n = it - p * 9;
        float orow = b_off[2 * n], ocol = b_off[2 * n + 1];
#pragma unroll
        for (int kq = 0; kq < 4; kq++) {
            orow += obuf[(kq * 32 + p) * 19 + n];
            ocol += obuf[(kq * 32 + p) * 19 + 9 + n];
        }
        float pr = (float)(h0 + (n / 3)) + orow;
        float pc = (float)(w0 + p + (n % 3)) + ocol;
        float flr = floorf(pr), flc = floorf(pc);
        float qlt_r = fminf(fmaxf(flr, 0.f), 129.f);
        float qlt_c = fminf(fmaxf(flc, 0.f), 129.f);
        float qrb_r = fminf(fmaxf(flr + 1.f, 0.f), 129.f);
        float qrb_c = fminf(fmaxf(flc + 1.f, 0.f), 129.f);
        bool mr = (pr < 1.f) || (pr > 128.f);
        bool mc = (pc < 1.f) || (pc > 128.f);
        float pr2 = mr ? flr : pr; pr2 = fminf(fmaxf(pr2, 0.f), 129.f);
        float pc2 = mc ? flc : pc; pc2 = fminf(fmaxf(pc2, 0.f), 129.f);
        float wr_lt = 1.f + (qlt_r - pr2);
        float wr_rb = 1.f - (qrb_r - pr2);
        float wc_lt = 1.f + (qlt_c - pc2);
        float wc_rb = 1.f - (qrb_c - pc2);
        int ilt_r = (int)qlt_r, ilt_c = (int)qlt_c;
        int irb_r = (int)qrb_r, irb_c = (int)qrb_c;
        cpkG[gbase + it] = (unsigned)ilt_r | ((unsigned)ilt_c << 8)
                         | ((unsigned)irb_r << 16) | ((unsigned)irb_c << 24);
        cwtG[gbase + it] = make_float4(wr_lt, wr_rb, wc_lt, wc_rb);
    }
}

// ---------------------------------------------------------------- K2b: gather + contraction MFMA
// block = 256 thr (4 waves), 32 pixels. P5 gather -> xs LDS. P6 MFMA (nt x kh). P7 combine+store.
// LDS = xs 37,120 B only (obuf2 aliases xs after MFMA reads) -> 4 blocks/CU.
__global__ __launch_bounds__(256) void gather_mfma(float* __restrict__ out,
                                                   const char* __restrict__ wsb) {
    const short8* Wb = (const short8*)(wsb + WBB_B);
    const unsigned* cpkG = (const unsigned*)(wsb + CPK_B);
    const float4*   cwtG = (const float4*)(wsb + CWT_B);

    __shared__ __attribute__((aligned(16))) char smem[37120];
    unsigned short* xs = (unsigned short*)smem;              // [32][580] bf16
    float* obuf2 = (float*)smem;                             // [2][32][33] = 8,448 B (after B2)

    int t = threadIdx.x;
    int lane = t & 63, wv = t >> 6;
    int pixbase = blockIdx.x * 32;
    int w0 = pixbase & 127, h0 = (pixbase >> 7) & 127, bimg = pixbase >> 14;
    int m = lane & 31, half8 = (lane >> 5) << 3;

    // ---- P5: gather (2 items/wave-load, half-wave per item; 128B coalesced corner rows)
    {
        int half = lane >> 5;
        int cp4 = (lane & 31) * 4;
        const char* bp = (const char*)(wsb + XPB_B) + (size_t)bimg * (130 * 130 * 128);
        char* xsb = (char*)xs;
        int base = blockIdx.x * 288 + wv * 72;
        int n5 = half;
        int sa = wv * 8 * (XS_STRIDE * 2) + n5 * 128;
#pragma unroll 4
        for (int i = 0; i < 36; i++) {
            int item = base + 2 * i + half;
            unsigned pk = cpkG[item];                        // uniform per half-wave, L2-hot
            float4 wt = cwtG[item];
            int rlt = pk & 255, clt = (pk >> 8) & 255, rrb = (pk >> 16) & 255, crb = pk >> 24;
            int aLT = rlt * 16640 + clt * 128;
            int aRB = rrb * 16640 + crb * 128;
            int aLB = rlt * 16640 + crb * 128;
            int aRT = rrb * 16640 + clt * 128;
            float Gx = wt.x * wt.z, Gy = wt.y * wt.w, Gz = wt.x * wt.w, Gw = wt.y * wt.z;
            unsigned int vlt = *(const unsigned int*)(bp + aLT + cp4);
            unsigned int vrb = *(const unsigned int*)(bp + aRB + cp4);
            unsigned int vlb = *(const unsigned int*)(bp + aLB + cp4);
            unsigned int vrt = *(const unsigned int*)(bp + aRT + cp4);
            float lo = fmaf(Gx, bflo2f(vlt), fmaf(Gy, bflo2f(vrb), fmaf(Gz, bflo2f(vlb), Gw * bflo2f(vrt))));
            float hi = fmaf(Gx, bfhi2f(vlt), fmaf(Gy, bfhi2f(vrb), fmaf(Gz, bfhi2f(vlb), Gw * bfhi2f(vrt))));
            __hip_bfloat162 pk2 = __float22bfloat162_rn(make_float2(lo, hi));
            *(unsigned int*)(xsb + sa + cp4) = *(unsigned int*)&pk2;
            n5 += 2; sa += 256;
            if (n5 >= 9) { n5 -= 9; sa += 8; }   // (p+1, n-9)
        }
    }
    __syncthreads();                                         // B1

    // ---- P6: contraction MFMA. wave: nt = N-tile (32 outs), kh = K-half (288)
    int nt = wv & 1, kh = wv >> 1;
    float16 acc;
#pragma unroll
    for (int r = 0; r < 16; r++) acc[r] = 0.f;
    for (int i2 = 0; i2 < 18; i2++) {
        int ksg = kh * 18 + i2;
        int baseE = m * XS_STRIDE + ksg * 16 + half8;
        short4_t a0 = *(const short4_t*)(xs + baseE);        // b64: stride 290dw -> 2-way only
        short4_t a1 = *(const short4_t*)(xs + baseE + 4);
        short8 af = __builtin_shufflevector(a0, a1, 0, 1, 2, 3, 4, 5, 6, 7);
        short8 bfv = Wb[(nt * 36 + ksg) * 64 + lane];        // coalesced 1KB, L2-resident
        acc = __builtin_amdgcn_mfma_f32_32x32x16_bf16(af, bfv, acc, 0, 0, 0);
    }
    __syncthreads();                                         // B2: all xs reads done
    // ---- P7: K-half combine (obuf2 aliases xs) + coalesced store
    if (kh == 1) {
#pragma unroll
        for (int r = 0; r < 16; r++) {
            int mrow = (r & 3) + 8 * (r >> 2) + 4 * (lane >> 5);
            obuf2[nt * 1056 + mrow * 33 + m] = acc[r];
        }
    }
    __syncthreads();                                         // B3
    if (kh == 0) {
#pragma unroll
        for (int r = 0; r < 16; r++) {
            int mrow = (r & 3) + 8 * (r >> 2) + 4 * (lane >> 5);
            int oi = nt * 1056 + mrow * 33 + m;
            obuf2[oi] = acc[r] + obuf2[oi];
        }
    }
    __syncthreads();                                         // B4
#pragma unroll
    for (int i = 0; i < 8; i++) {
        int lin = i * 256 + t;
        int o = lin >> 5, p = lin & 31;
        float v = obuf2[(o >> 5) * 1056 + p * 33 + (o & 31)];
        out[((bimg * 64 + o) << 14) + (h0 << 7) + w0 + p] = v;
    }
}

// ---------------------------------------------------------------- launch
extern "C" void kernel_launch(void* const* d_in, const int* in_sizes, int n_in,
                              void* d_out, int out_size, void* d_ws, size_t ws_size,
                              hipStream_t stream) {
    const float* x      = (const float*)d_in[0];
    const float* W_off  = (const float*)d_in[1];
    const float* b_off  = (const float*)d_in[2];
    const float* W_conv = (const float*)d_in[3];
    char* wsb  = (char*)d_ws;            // needs 29,249,536 B
    float* out = (float*)d_out;

    hipLaunchKernelGGL(pad_prep, dim3(536), dim3(1024), 0, stream, x, W_off, W_conv, wsb);
    hipLaunchKernelGGL(offset_setup, dim3(NPIX / 32), dim3(256), 0, stream, b_off, wsb);
    hipLaunchKernelGGL(gather_mfma, dim3(NPIX / 32), dim3(256), 0, stream, out, wsb);
}